// Round 8
// baseline (1193.262 us; speedup 1.0000x reference)
//
#include <hip/hip_runtime.h>
#include <hip/hip_bf16.h>

// ---------------------------------------------------------------------------
// GCN forward, 4x GraphConv norm='both'. N=50000, E=800000, 256->512->512->512->40
// R7 (re-run; previous bench was a broker capacity timeout): all inter-stage
// tensors fp16. Aggregation: gather fp16, fp32 accum, write fp16 (no split).
// GEMM: A = fp16 direct (exact), W split into fp16-hi + fp16-lo*4096,
// 2-term f16 MFMA with dual accumulators.
// ---------------------------------------------------------------------------

#define GCN_N 50000
#define GCN_E 800000

typedef unsigned short u16;
typedef __attribute__((ext_vector_type(4))) float f32x4;
typedef __attribute__((ext_vector_type(4))) _Float16 f16x4;
typedef __attribute__((ext_vector_type(8))) _Float16 f16x8;

__device__ __forceinline__ void gload_lds16(const void* g, void* l) {
  __builtin_amdgcn_global_load_lds((const __attribute__((address_space(1))) void*)g,
                                   (__attribute__((address_space(3))) void*)l, 16, 0, 0);
}

// ---------------- CSR build ----------------

__global__ void hist_kernel(const int* __restrict__ src, const int* __restrict__ dst,
                            int* __restrict__ deg_src, int* __restrict__ deg_dst, int E) {
  int i = blockIdx.x * blockDim.x + threadIdx.x;
  if (i < E) {
    atomicAdd(&deg_src[src[i]], 1);
    atomicAdd(&deg_dst[dst[i]], 1);
  }
}

__global__ void cinv_kernel(const int* __restrict__ deg_src, const int* __restrict__ deg_dst,
                            float* __restrict__ c_src, float* __restrict__ c_dst, int n) {
  int i = blockIdx.x * blockDim.x + threadIdx.x;
  if (i < n) {
    int ds = deg_src[i];
    int dd = deg_dst[i];
    c_src[i] = ds > 0 ? 1.0f / sqrtf((float)ds) : 0.0f;
    c_dst[i] = dd > 0 ? 1.0f / sqrtf((float)dd) : 0.0f;
  }
}

__global__ void scan_kernel(const int* __restrict__ deg, int* __restrict__ row_ptr,
                            int* __restrict__ cursor, int n) {
  __shared__ int wsum[16];
  __shared__ int s_carry;
  int lane = threadIdx.x & 63;
  int wid = threadIdx.x >> 6;
  if (threadIdx.x == 0) s_carry = 0;
  __syncthreads();
  for (int base = 0; base < n; base += 1024) {
    int i = base + (int)threadIdx.x;
    int v = (i < n) ? deg[i] : 0;
    int x = v;
    #pragma unroll
    for (int off = 1; off < 64; off <<= 1) {
      int y = __shfl_up(x, off, 64);
      if (lane >= off) x += y;
    }
    if (lane == 63) wsum[wid] = x;
    __syncthreads();
    int woff = s_carry;
    for (int w = 0; w < wid; ++w) woff += wsum[w];
    int incl = woff + x;
    if (i < n) {
      row_ptr[i] = incl - v;
      cursor[i] = incl - v;
    }
    __syncthreads();
    if (threadIdx.x == 1023) s_carry = incl;
    __syncthreads();
  }
  if (threadIdx.x == 0) row_ptr[n] = s_carry;
}

__global__ void fill_csr_kernel(const int* __restrict__ src, const int* __restrict__ dst,
                                int* __restrict__ cursor, int* __restrict__ csr_src, int E) {
  int i = blockIdx.x * blockDim.x + threadIdx.x;
  if (i < E) {
    int slot = atomicAdd(&cursor[dst[i]], 1);
    csr_src[slot] = src[i];
  }
}

// ---------------- fp32 -> fp16 convert ----------------

__global__ void f32_to_f16_kernel(const float* __restrict__ in, _Float16* __restrict__ out,
                                  long n4) {
  long i = (long)blockIdx.x * blockDim.x + threadIdx.x;
  long stride = (long)gridDim.x * blockDim.x;
  for (; i < n4; i += stride) {
    float4 v = ((const float4*)in)[i];
    f16x4 h;
    h.x = (_Float16)v.x; h.y = (_Float16)v.y; h.z = (_Float16)v.z; h.w = (_Float16)v.w;
    ((f16x4*)out)[i] = h;
  }
}

// ---------------- aggregation (fp16 in, fp32 accum, fp16 out) ----------------
// One block per dst node; thread t owns vector group t of G. 1-deep prefetch.
template <typename VT, int NE, int G>
__global__ void agg16_kernel(const _Float16* __restrict__ in, _Float16* __restrict__ out,
                             const int* __restrict__ row_ptr, const int* __restrict__ csr_src,
                             const float* __restrict__ c_src, const float* __restrict__ c_dst) {
  int d = blockIdx.x;
  int t = threadIdx.x;
  if (t >= G) return;
  int beg = row_ptr[d];
  int end = row_ptr[d + 1];
  const VT* inv = (const VT*)in;
  float acc[NE];
  #pragma unroll
  for (int e = 0; e < NE; ++e) acc[e] = 0.f;
  int s_cur = 0; float c_cur = 0.f;
  if (beg < end) { s_cur = csr_src[beg]; c_cur = c_src[s_cur]; }
  for (int k = beg; k < end; ++k) {
    int s_nxt = 0; float c_nxt = 0.f;
    if (k + 1 < end) { s_nxt = csr_src[k + 1]; c_nxt = c_src[s_nxt]; }
    VT v = inv[(size_t)s_cur * G + t];
    #pragma unroll
    for (int e = 0; e < NE; ++e) acc[e] = fmaf(c_cur, (float)v[e], acc[e]);
    s_cur = s_nxt; c_cur = c_nxt;
  }
  float cd = c_dst[d];
  VT o;
  #pragma unroll
  for (int e = 0; e < NE; ++e) o[e] = (_Float16)(acc[e] * cd);
  ((VT*)out)[(size_t)d * G + t] = o;
}

// fp16 in -> fp32 out with bias (final 40-dim aggregation).
__global__ void agg40_kernel(const _Float16* __restrict__ in, float* __restrict__ out,
                             const int* __restrict__ row_ptr, const int* __restrict__ csr_src,
                             const float* __restrict__ c_src, const float* __restrict__ c_dst,
                             const float* __restrict__ bias) {
  int d = blockIdx.x;
  int t = threadIdx.x;
  if (t >= 10) return;
  int beg = row_ptr[d];
  int end = row_ptr[d + 1];
  const f16x4* in4 = (const f16x4*)in;
  float ax = 0.f, ay = 0.f, az = 0.f, aw = 0.f;
  int s_cur = 0; float c_cur = 0.f;
  if (beg < end) { s_cur = csr_src[beg]; c_cur = c_src[s_cur]; }
  for (int k = beg; k < end; ++k) {
    int s_nxt = 0; float c_nxt = 0.f;
    if (k + 1 < end) { s_nxt = csr_src[k + 1]; c_nxt = c_src[s_nxt]; }
    f16x4 v = in4[(size_t)s_cur * 10 + t];
    ax = fmaf(c_cur, (float)v.x, ax);
    ay = fmaf(c_cur, (float)v.y, ay);
    az = fmaf(c_cur, (float)v.z, az);
    aw = fmaf(c_cur, (float)v.w, aw);
    s_cur = s_nxt; c_cur = c_nxt;
  }
  float cd = c_dst[d];
  float4 b = ((const float4*)bias)[t];
  float4 o;
  o.x = ax * cd + b.x;
  o.y = ay * cd + b.y;
  o.z = az * cd + b.z;
  o.w = aw * cd + b.w;
  ((float4*)out)[(size_t)d * 10 + t] = o;
}

// ---------------- weight prep: W[K][N] fp32 -> Wt hi/lo fp16 [N][K] ----------------
// hi = fp16(W); lo = fp16((W - hi) * 4096)  (scaled to stay in fp16 normal range)

__global__ void prep_weight_kernel(const float* __restrict__ W, _Float16* __restrict__ th,
                                   _Float16* __restrict__ tl, int K, int N) {
  __shared__ float tile[32][33];
  int bn = blockIdx.x * 32, bk = blockIdx.y * 32;
  int tx = threadIdx.x, ty = threadIdx.y;  // (32, 8)
  #pragma unroll
  for (int i = 0; i < 4; ++i)
    tile[ty + i * 8][tx] = W[(size_t)(bk + ty + i * 8) * N + bn + tx];
  __syncthreads();
  #pragma unroll
  for (int i = 0; i < 4; ++i) {
    float v = tile[tx][ty + i * 8];           // = W[bk+tx][bn+ty+i*8]
    _Float16 h = (_Float16)v;
    _Float16 l = (_Float16)((v - (float)h) * 4096.f);
    size_t o = (size_t)(bn + ty + i * 8) * K + bk + tx;  // Wt[n][k], k coalesced
    th[o] = h;
    tl[o] = l;
  }
}

// ---------------- 2-term fp16 MFMA GEMM ----------------
// C16[M][N] = relu( A[M][K](fp16) * (Bh + Bl/4096)^T[N][K] + bias )
// 128x128 tile, BK=32, 4 waves (2x2), 4x4 16x16x32_f16 frags, dual accumulators.
// Linear LDS + source-pre-swizzle (chunk ^= (row&3)^((row>>2)&3)) -> <=2-way conflicts.
__global__ __launch_bounds__(256) void mfma_gemm_kernel(
    const _Float16* __restrict__ A,
    const _Float16* __restrict__ Bh, const _Float16* __restrict__ Bl,
    const float* __restrict__ bias, _Float16* __restrict__ C,
    int M, int K, int N) {
  __shared__ _Float16 sA[128 * 32], sBh[128 * 32], sBl[128 * 32];
  int t = threadIdx.x;
  int lane = t & 63, wid = t >> 6;
  int wr = wid >> 1, wc = wid & 1;
  int lr = lane & 15, ko = lane >> 4;
  int swz = (lr & 3) ^ ((lr >> 2) & 3);
  int koff = ((ko ^ swz) << 3);  // fp16 units within a 32-elem row
  int bm = blockIdx.x * 128, bn = blockIdx.y * 128;

  f32x4 acch[4][4] = {};
  f32x4 accl[4][4] = {};

  int aoff[4], boff[4];
  #pragma unroll
  for (int rb = 0; rb < 4; ++rb) {
    aoff[rb] = (wr * 64 + rb * 16 + lr) * 32 + koff;
    boff[rb] = (wc * 64 + rb * 16 + lr) * 32 + koff;
  }

  for (int k0 = 0; k0 < K; k0 += 32) {
    #pragma unroll
    for (int it = 0; it < 2; ++it) {
      int q = it * 256 + t;
      int row = q >> 2;
      int c = (q & 3) ^ ((row & 3) ^ ((row >> 2) & 3));
      int ldst = it * 2048 + wid * 512;  // fp16 units, wave-uniform base
      int gra = bm + row;
      if (gra >= M) gra = M - 1;
      size_t ga = (size_t)gra * K + k0 + c * 8;
      gload_lds16(A + ga, sA + ldst);
      size_t gb = (size_t)(bn + row) * K + k0 + c * 8;  // N%128==0 for these layers
      gload_lds16(Bh + gb, sBh + ldst);
      gload_lds16(Bl + gb, sBl + ldst);
    }
    __syncthreads();
    f16x8 a[4], bh[4], bl[4];
    #pragma unroll
    for (int i = 0; i < 4; ++i) {
      a[i]  = *(const f16x8*)(sA + aoff[i]);
      bh[i] = *(const f16x8*)(sBh + boff[i]);
      bl[i] = *(const f16x8*)(sBl + boff[i]);
    }
    #pragma unroll
    for (int i = 0; i < 4; ++i)
      #pragma unroll
      for (int j = 0; j < 4; ++j) {
        acch[i][j] = __builtin_amdgcn_mfma_f32_16x16x32_f16(a[i], bh[j], acch[i][j], 0, 0, 0);
        accl[i][j] = __builtin_amdgcn_mfma_f32_16x16x32_f16(a[i], bl[j], accl[i][j], 0, 0, 0);
      }
    __syncthreads();
  }

  const float inv_s = 1.0f / 4096.0f;
  int r0 = (lane >> 4) << 2;
  #pragma unroll
  for (int i = 0; i < 4; ++i) {
    #pragma unroll
    for (int j = 0; j < 4; ++j) {
      int col = bn + wc * 64 + j * 16 + lr;
      float bv = bias[col];
      #pragma unroll
      for (int r = 0; r < 4; ++r) {
        int row = bm + wr * 64 + i * 16 + r0 + r;
        if (row < M) {
          float v = acch[i][j][r] + accl[i][j][r] * inv_s + bv;
          v = v > 0.f ? v : 0.f;
          C[(size_t)row * N + col] = (_Float16)v;
        }
      }
    }
  }
}

// ---------------- fp32 VALU GEMM, fp16 A and C (layer 4, N=40) ----------------

__global__ __launch_bounds__(256) void gemm40_kernel(const _Float16* __restrict__ A,
                                                     const float* __restrict__ W,
                                                     _Float16* __restrict__ C,
                                                     int M, int K, int N) {
  __shared__ float As[16][128 + 4];
  __shared__ float Bs[16][128 + 4];
  int tid = threadIdx.x;
  int tx = tid & 15;
  int ty = tid >> 4;
  int bm = blockIdx.x * 128;
  int bn = blockIdx.y * 128;

  float acc[8][8];
  #pragma unroll
  for (int i = 0; i < 8; ++i)
    #pragma unroll
    for (int j = 0; j < 8; ++j) acc[i][j] = 0.f;

  int ar = tid >> 2;
  int akq = (tid & 3) << 2;
  int bkk = tid >> 4;
  int bcq = (tid & 15) << 2;

  for (int k0 = 0; k0 < K; k0 += 16) {
    #pragma unroll
    for (int half = 0; half < 2; ++half) {
      int r = ar + half * 64;
      int grow = bm + r;
      float4 v = make_float4(0.f, 0.f, 0.f, 0.f);
      if (grow < M) {
        f16x4 hv = *(const f16x4*)&A[(size_t)grow * K + k0 + akq];
        v = make_float4((float)hv.x, (float)hv.y, (float)hv.z, (float)hv.w);
      }
      As[akq + 0][r] = v.x;
      As[akq + 1][r] = v.y;
      As[akq + 2][r] = v.z;
      As[akq + 3][r] = v.w;
    }
    #pragma unroll
    for (int half = 0; half < 2; ++half) {
      int c = bcq + half * 64;
      int gc = bn + c;
      float4 v = make_float4(0.f, 0.f, 0.f, 0.f);
      if (gc + 3 < N) v = *(const float4*)&W[(size_t)(k0 + bkk) * N + gc];
      *(float4*)&Bs[bkk][c] = v;
    }
    __syncthreads();
    #pragma unroll
    for (int kk = 0; kk < 16; ++kk) {
      float4 a0 = *(const float4*)&As[kk][ty * 4];
      float4 a1 = *(const float4*)&As[kk][ty * 4 + 64];
      float4 b0 = *(const float4*)&Bs[kk][tx * 4];
      float4 b1 = *(const float4*)&Bs[kk][tx * 4 + 64];
      float a[8] = {a0.x, a0.y, a0.z, a0.w, a1.x, a1.y, a1.z, a1.w};
      float b[8] = {b0.x, b0.y, b0.z, b0.w, b1.x, b1.y, b1.z, b1.w};
      #pragma unroll
      for (int i = 0; i < 8; ++i)
        #pragma unroll
        for (int j = 0; j < 8; ++j) acc[i][j] = fmaf(a[i], b[j], acc[i][j]);
    }
    __syncthreads();
  }

  #pragma unroll
  for (int i = 0; i < 8; ++i) {
    int r = bm + (i < 4 ? ty * 4 + i : 64 + ty * 4 + (i - 4));
    if (r >= M) continue;
    #pragma unroll
    for (int j = 0; j < 8; ++j) {
      int c = bn + (j < 4 ? tx * 4 + j : 64 + tx * 4 + (j - 4));
      if (c >= N) continue;
      C[(size_t)r * N + c] = (_Float16)acc[i][j];
    }
  }
}

// ---------------- launch ----------------

extern "C" void kernel_launch(void* const* d_in, const int* in_sizes, int n_in,
                              void* d_out, int out_size, void* d_ws, size_t ws_size,
                              hipStream_t stream) {
  const float* x  = (const float*)d_in[0];
  const int* src  = (const int*)d_in[1];
  const int* dst  = (const int*)d_in[2];
  const float* W1 = (const float*)d_in[3];
  const float* b1 = (const float*)d_in[4];
  const float* W2 = (const float*)d_in[5];
  const float* b2 = (const float*)d_in[6];
  const float* W3 = (const float*)d_in[7];
  const float* b3 = (const float*)d_in[8];
  const float* W4 = (const float*)d_in[9];
  const float* b4 = (const float*)d_in[10];
  float* out = (float*)d_out;

  const int N = GCN_N, E = GCN_E;

  char* ws = (char*)d_ws;
  size_t off = 0;
  _Float16* h16a = (_Float16*)(ws + off); off += (size_t)N * 512 * 2;  // agg out / GEMM A
  _Float16* h16b = (_Float16*)(ws + off); off += (size_t)N * 512 * 2;  // GEMM out / agg in
  _Float16* x16  = (_Float16*)(ws + off); off += (size_t)N * 256 * 2;
  float* c_src = (float*)(ws + off); off += (size_t)N * 4;
  float* c_dst = (float*)(ws + off); off += (size_t)N * 4;
  int* row_ptr = (int*)(ws + off); off += (size_t)(N + 4) * 4;
  int* csr_src = (int*)(ws + off); off += (size_t)E * 4;
  _Float16* WtH1 = (_Float16*)(ws + off); off += (size_t)512 * 256 * 2;
  _Float16* WtL1 = (_Float16*)(ws + off); off += (size_t)512 * 256 * 2;
  _Float16* WtH2 = (_Float16*)(ws + off); off += (size_t)512 * 512 * 2;
  _Float16* WtL2 = (_Float16*)(ws + off); off += (size_t)512 * 512 * 2;
  _Float16* WtH3 = (_Float16*)(ws + off); off += (size_t)512 * 512 * 2;
  _Float16* WtL3 = (_Float16*)(ws + off); off += (size_t)512 * 512 * 2;
  // transients alias h16a (dead before L1 agg writes h16a)
  int* deg_src = (int*)h16a;
  int* deg_dst = deg_src + N;
  int* cursor  = deg_dst + N;
  // t4 [N][40] fp16 aliases x16 (x16 dead after L1 agg)
  _Float16* t4 = x16;

  hipMemsetAsync(deg_src, 0, (size_t)2 * N * 4, stream);
  hist_kernel<<<(E + 255) / 256, 256, 0, stream>>>(src, dst, deg_src, deg_dst, E);
  cinv_kernel<<<(N + 255) / 256, 256, 0, stream>>>(deg_src, deg_dst, c_src, c_dst, N);
  scan_kernel<<<1, 1024, 0, stream>>>(deg_dst, row_ptr, cursor, N);
  fill_csr_kernel<<<(E + 255) / 256, 256, 0, stream>>>(src, dst, cursor, csr_src, E);

  prep_weight_kernel<<<dim3(16, 8), dim3(32, 8), 0, stream>>>(W1, WtH1, WtL1, 256, 512);
  prep_weight_kernel<<<dim3(16, 16), dim3(32, 8), 0, stream>>>(W2, WtH2, WtL2, 512, 512);
  prep_weight_kernel<<<dim3(16, 16), dim3(32, 8), 0, stream>>>(W3, WtH3, WtL3, 512, 512);

  f32_to_f16_kernel<<<2048, 256, 0, stream>>>(x, x16, (long)N * 256 / 4);

  int gm = (N + 127) / 128;  // 391

  // L1: agg 256-dim (f16x4, 64 thr), GEMM K=256
  agg16_kernel<f16x4, 4, 64><<<N, 64, 0, stream>>>(x16, h16a, row_ptr, csr_src, c_src, c_dst);
  mfma_gemm_kernel<<<dim3(gm, 4), 256, 0, stream>>>(h16a, WtH1, WtL1, b1, h16b, N, 256, 512);
  // L2: agg 512-dim (f16x8, 64 thr = 16B/lane)
  agg16_kernel<f16x8, 8, 64><<<N, 64, 0, stream>>>(h16b, h16a, row_ptr, csr_src, c_src, c_dst);
  mfma_gemm_kernel<<<dim3(gm, 4), 256, 0, stream>>>(h16a, WtH2, WtL2, b2, h16b, N, 512, 512);
  // L3
  agg16_kernel<f16x8, 8, 64><<<N, 64, 0, stream>>>(h16b, h16a, row_ptr, csr_src, c_src, c_dst);
  mfma_gemm_kernel<<<dim3(gm, 4), 256, 0, stream>>>(h16a, WtH3, WtL3, b3, h16b, N, 512, 512);
  // L4
  gemm40_kernel<<<dim3(gm, 1), 256, 0, stream>>>(h16b, W4, t4, N, 512, 40);
  agg40_kernel<<<N, 64, 0, stream>>>(t4, out, row_ptr, csr_src, c_src, c_dst, b4);
}

// Round 11
// 961.919 us; speedup vs baseline: 1.2405x; 1.2405x over previous
//
#include <hip/hip_runtime.h>
#include <hip/hip_bf16.h>

// ---------------------------------------------------------------------------
// GCN forward, 4x GraphConv norm='both'. N=50000, E=800000, 256->512->512->512->40
// R9 (re-run x2; previous benches were broker capacity timeouts): same numerics
// as R7 (fp16 activations; W = fp16-hi + fp16-lo*4096, 2-term f16 MFMA). GEMM
// restructured to 512 thr / 8 waves so per-thread accumulator = 64 regs
// (was 128) -> 2 blocks/CU occupancy restored.
// ---------------------------------------------------------------------------

#define GCN_N 50000
#define GCN_E 800000

typedef unsigned short u16;
typedef __attribute__((ext_vector_type(4))) float f32x4;
typedef __attribute__((ext_vector_type(4))) _Float16 f16x4;
typedef __attribute__((ext_vector_type(8))) _Float16 f16x8;

__device__ __forceinline__ void gload_lds16(const void* g, void* l) {
  __builtin_amdgcn_global_load_lds((const __attribute__((address_space(1))) void*)g,
                                   (__attribute__((address_space(3))) void*)l, 16, 0, 0);
}

// ---------------- CSR build ----------------

__global__ void hist_kernel(const int* __restrict__ src, const int* __restrict__ dst,
                            int* __restrict__ deg_src, int* __restrict__ deg_dst, int E) {
  int i = blockIdx.x * blockDim.x + threadIdx.x;
  if (i < E) {
    atomicAdd(&deg_src[src[i]], 1);
    atomicAdd(&deg_dst[dst[i]], 1);
  }
}

__global__ void cinv_kernel(const int* __restrict__ deg_src, const int* __restrict__ deg_dst,
                            float* __restrict__ c_src, float* __restrict__ c_dst, int n) {
  int i = blockIdx.x * blockDim.x + threadIdx.x;
  if (i < n) {
    int ds = deg_src[i];
    int dd = deg_dst[i];
    c_src[i] = ds > 0 ? 1.0f / sqrtf((float)ds) : 0.0f;
    c_dst[i] = dd > 0 ? 1.0f / sqrtf((float)dd) : 0.0f;
  }
}

__global__ void scan_kernel(const int* __restrict__ deg, int* __restrict__ row_ptr,
                            int* __restrict__ cursor, int n) {
  __shared__ int wsum[16];
  __shared__ int s_carry;
  int lane = threadIdx.x & 63;
  int wid = threadIdx.x >> 6;
  if (threadIdx.x == 0) s_carry = 0;
  __syncthreads();
  for (int base = 0; base < n; base += 1024) {
    int i = base + (int)threadIdx.x;
    int v = (i < n) ? deg[i] : 0;
    int x = v;
    #pragma unroll
    for (int off = 1; off < 64; off <<= 1) {
      int y = __shfl_up(x, off, 64);
      if (lane >= off) x += y;
    }
    if (lane == 63) wsum[wid] = x;
    __syncthreads();
    int woff = s_carry;
    for (int w = 0; w < wid; ++w) woff += wsum[w];
    int incl = woff + x;
    if (i < n) {
      row_ptr[i] = incl - v;
      cursor[i] = incl - v;
    }
    __syncthreads();
    if (threadIdx.x == 1023) s_carry = incl;
    __syncthreads();
  }
  if (threadIdx.x == 0) row_ptr[n] = s_carry;
}

__global__ void fill_csr_kernel(const int* __restrict__ src, const int* __restrict__ dst,
                                int* __restrict__ cursor, int* __restrict__ csr_src, int E) {
  int i = blockIdx.x * blockDim.x + threadIdx.x;
  if (i < E) {
    int slot = atomicAdd(&cursor[dst[i]], 1);
    csr_src[slot] = src[i];
  }
}

// ---------------- fp32 -> fp16 convert ----------------

__global__ void f32_to_f16_kernel(const float* __restrict__ in, _Float16* __restrict__ out,
                                  long n4) {
  long i = (long)blockIdx.x * blockDim.x + threadIdx.x;
  long stride = (long)gridDim.x * blockDim.x;
  for (; i < n4; i += stride) {
    float4 v = ((const float4*)in)[i];
    f16x4 h;
    h.x = (_Float16)v.x; h.y = (_Float16)v.y; h.z = (_Float16)v.z; h.w = (_Float16)v.w;
    ((f16x4*)out)[i] = h;
  }
}

// ---------------- aggregation (fp16 in, fp32 accum, fp16 out) ----------------
template <typename VT, int NE, int G>
__global__ void agg16_kernel(const _Float16* __restrict__ in, _Float16* __restrict__ out,
                             const int* __restrict__ row_ptr, const int* __restrict__ csr_src,
                             const float* __restrict__ c_src, const float* __restrict__ c_dst) {
  int d = blockIdx.x;
  int t = threadIdx.x;
  if (t >= G) return;
  int beg = row_ptr[d];
  int end = row_ptr[d + 1];
  const VT* inv = (const VT*)in;
  float acc[NE];
  #pragma unroll
  for (int e = 0; e < NE; ++e) acc[e] = 0.f;
  int s_cur = 0; float c_cur = 0.f;
  if (beg < end) { s_cur = csr_src[beg]; c_cur = c_src[s_cur]; }
  for (int k = beg; k < end; ++k) {
    int s_nxt = 0; float c_nxt = 0.f;
    if (k + 1 < end) { s_nxt = csr_src[k + 1]; c_nxt = c_src[s_nxt]; }
    VT v = inv[(size_t)s_cur * G + t];
    #pragma unroll
    for (int e = 0; e < NE; ++e) acc[e] = fmaf(c_cur, (float)v[e], acc[e]);
    s_cur = s_nxt; c_cur = c_nxt;
  }
  float cd = c_dst[d];
  VT o;
  #pragma unroll
  for (int e = 0; e < NE; ++e) o[e] = (_Float16)(acc[e] * cd);
  ((VT*)out)[(size_t)d * G + t] = o;
}

// fp16 in -> fp32 out with bias (final 40-dim aggregation).
__global__ void agg40_kernel(const _Float16* __restrict__ in, float* __restrict__ out,
                             const int* __restrict__ row_ptr, const int* __restrict__ csr_src,
                             const float* __restrict__ c_src, const float* __restrict__ c_dst,
                             const float* __restrict__ bias) {
  int d = blockIdx.x;
  int t = threadIdx.x;
  if (t >= 10) return;
  int beg = row_ptr[d];
  int end = row_ptr[d + 1];
  const f16x4* in4 = (const f16x4*)in;
  float ax = 0.f, ay = 0.f, az = 0.f, aw = 0.f;
  int s_cur = 0; float c_cur = 0.f;
  if (beg < end) { s_cur = csr_src[beg]; c_cur = c_src[s_cur]; }
  for (int k = beg; k < end; ++k) {
    int s_nxt = 0; float c_nxt = 0.f;
    if (k + 1 < end) { s_nxt = csr_src[k + 1]; c_nxt = c_src[s_nxt]; }
    f16x4 v = in4[(size_t)s_cur * 10 + t];
    ax = fmaf(c_cur, (float)v.x, ax);
    ay = fmaf(c_cur, (float)v.y, ay);
    az = fmaf(c_cur, (float)v.z, az);
    aw = fmaf(c_cur, (float)v.w, aw);
    s_cur = s_nxt; c_cur = c_nxt;
  }
  float cd = c_dst[d];
  float4 b = ((const float4*)bias)[t];
  float4 o;
  o.x = ax * cd + b.x;
  o.y = ay * cd + b.y;
  o.z = az * cd + b.z;
  o.w = aw * cd + b.w;
  ((float4*)out)[(size_t)d * 10 + t] = o;
}

// ---------------- weight prep: W[K][N] fp32 -> Wt hi/lo fp16 [N][K] ----------------

__global__ void prep_weight_kernel(const float* __restrict__ W, _Float16* __restrict__ th,
                                   _Float16* __restrict__ tl, int K, int N) {
  __shared__ float tile[32][33];
  int bn = blockIdx.x * 32, bk = blockIdx.y * 32;
  int tx = threadIdx.x, ty = threadIdx.y;  // (32, 8)
  #pragma unroll
  for (int i = 0; i < 4; ++i)
    tile[ty + i * 8][tx] = W[(size_t)(bk + ty + i * 8) * N + bn + tx];
  __syncthreads();
  #pragma unroll
  for (int i = 0; i < 4; ++i) {
    float v = tile[tx][ty + i * 8];           // = W[bk+tx][bn+ty+i*8]
    _Float16 h = (_Float16)v;
    _Float16 l = (_Float16)((v - (float)h) * 4096.f);
    size_t o = (size_t)(bn + ty + i * 8) * K + bk + tx;  // Wt[n][k], k coalesced
    th[o] = h;
    tl[o] = l;
  }
}

// ---------------- 2-term fp16 MFMA GEMM, 8 waves ----------------
// C16[M][N] = relu( A[M][K](fp16) * (Bh + Bl/4096)^T[N][K] + bias )
// 128x128 tile, BK=32, 512 thr = 8 waves (2Mx4N), each wave 64x32 out
// (4x2 frags of 16x16x32_f16, dual acc = 64 regs/thread).
__global__ __launch_bounds__(512, 4) void mfma_gemm_kernel(
    const _Float16* __restrict__ A,
    const _Float16* __restrict__ Bh, const _Float16* __restrict__ Bl,
    const float* __restrict__ bias, _Float16* __restrict__ C,
    int M, int K, int N) {
  __shared__ _Float16 sA[128 * 32], sBh[128 * 32], sBl[128 * 32];
  int t = threadIdx.x;
  int lane = t & 63, wid = t >> 6;
  int wr = wid >> 2, wc = wid & 3;        // 2 x 4 wave grid
  int lr = lane & 15, ko = lane >> 4;
  int swz = (lr & 3) ^ ((lr >> 2) & 3);
  int koff = ((ko ^ swz) << 3);           // fp16 units within a 32-elem row
  int bm = blockIdx.x * 128, bn = blockIdx.y * 128;

  f32x4 acch[4][2] = {};
  f32x4 accl[4][2] = {};

  int aoff[4], boff[2];
  #pragma unroll
  for (int i = 0; i < 4; ++i) aoff[i] = (wr * 64 + i * 16 + lr) * 32 + koff;
  #pragma unroll
  for (int j = 0; j < 2; ++j) boff[j] = (wc * 32 + j * 16 + lr) * 32 + koff;

  // staging: q = t (0..511), row = q>>2, chunk c pre-swizzled; one pass per array
  int srow = t >> 2;
  int sc = (t & 3) ^ ((srow & 3) ^ ((srow >> 2) & 3));
  int ldst = wid * 512;  // fp16 units; wave-uniform base, lane*16B implicit
  int gra = bm + srow;
  if (gra >= M) gra = M - 1;
  size_t gabase = (size_t)gra * K + sc * 8;
  size_t gbbase = (size_t)(bn + srow) * K + sc * 8;  // N%128==0 for these layers

  for (int k0 = 0; k0 < K; k0 += 32) {
    gload_lds16(A + gabase + k0, sA + ldst);
    gload_lds16(Bh + gbbase + k0, sBh + ldst);
    gload_lds16(Bl + gbbase + k0, sBl + ldst);
    __syncthreads();
    f16x8 a[4], bh[2], bl[2];
    #pragma unroll
    for (int i = 0; i < 4; ++i) a[i] = *(const f16x8*)(sA + aoff[i]);
    #pragma unroll
    for (int j = 0; j < 2; ++j) {
      bh[j] = *(const f16x8*)(sBh + boff[j]);
      bl[j] = *(const f16x8*)(sBl + boff[j]);
    }
    #pragma unroll
    for (int i = 0; i < 4; ++i)
      #pragma unroll
      for (int j = 0; j < 2; ++j) {
        acch[i][j] = __builtin_amdgcn_mfma_f32_16x16x32_f16(a[i], bh[j], acch[i][j], 0, 0, 0);
        accl[i][j] = __builtin_amdgcn_mfma_f32_16x16x32_f16(a[i], bl[j], accl[i][j], 0, 0, 0);
      }
    __syncthreads();
  }

  const float inv_s = 1.0f / 4096.0f;
  int r0 = (lane >> 4) << 2;
  #pragma unroll
  for (int i = 0; i < 4; ++i) {
    #pragma unroll
    for (int j = 0; j < 2; ++j) {
      int col = bn + wc * 32 + j * 16 + lr;
      float bv = bias[col];
      #pragma unroll
      for (int r = 0; r < 4; ++r) {
        int row = bm + wr * 64 + i * 16 + r0 + r;
        if (row < M) {
          float v = acch[i][j][r] + accl[i][j][r] * inv_s + bv;
          v = v > 0.f ? v : 0.f;
          C[(size_t)row * N + col] = (_Float16)v;
        }
      }
    }
  }
}

// ---------------- fp32 VALU GEMM, fp16 A and C (layer 4, N=40) ----------------

__global__ __launch_bounds__(256) void gemm40_kernel(const _Float16* __restrict__ A,
                                                     const float* __restrict__ W,
                                                     _Float16* __restrict__ C,
                                                     int M, int K, int N) {
  __shared__ float As[16][128 + 4];
  __shared__ float Bs[16][128 + 4];
  int tid = threadIdx.x;
  int tx = tid & 15;
  int ty = tid >> 4;
  int bm = blockIdx.x * 128;
  int bn = blockIdx.y * 128;

  float acc[8][8];
  #pragma unroll
  for (int i = 0; i < 8; ++i)
    #pragma unroll
    for (int j = 0; j < 8; ++j) acc[i][j] = 0.f;

  int ar = tid >> 2;
  int akq = (tid & 3) << 2;
  int bkk = tid >> 4;
  int bcq = (tid & 15) << 2;

  for (int k0 = 0; k0 < K; k0 += 16) {
    #pragma unroll
    for (int half = 0; half < 2; ++half) {
      int r = ar + half * 64;
      int grow = bm + r;
      float4 v = make_float4(0.f, 0.f, 0.f, 0.f);
      if (grow < M) {
        f16x4 hv = *(const f16x4*)&A[(size_t)grow * K + k0 + akq];
        v = make_float4((float)hv.x, (float)hv.y, (float)hv.z, (float)hv.w);
      }
      As[akq + 0][r] = v.x;
      As[akq + 1][r] = v.y;
      As[akq + 2][r] = v.z;
      As[akq + 3][r] = v.w;
    }
    #pragma unroll
    for (int half = 0; half < 2; ++half) {
      int c = bcq + half * 64;
      int gc = bn + c;
      float4 v = make_float4(0.f, 0.f, 0.f, 0.f);
      if (gc + 3 < N) v = *(const float4*)&W[(size_t)(k0 + bkk) * N + gc];
      *(float4*)&Bs[bkk][c] = v;
    }
    __syncthreads();
    #pragma unroll
    for (int kk = 0; kk < 16; ++kk) {
      float4 a0 = *(const float4*)&As[kk][ty * 4];
      float4 a1 = *(const float4*)&As[kk][ty * 4 + 64];
      float4 b0 = *(const float4*)&Bs[kk][tx * 4];
      float4 b1 = *(const float4*)&Bs[kk][tx * 4 + 64];
      float a[8] = {a0.x, a0.y, a0.z, a0.w, a1.x, a1.y, a1.z, a1.w};
      float b[8] = {b0.x, b0.y, b0.z, b0.w, b1.x, b1.y, b1.z, b1.w};
      #pragma unroll
      for (int i = 0; i < 8; ++i)
        #pragma unroll
        for (int j = 0; j < 8; ++j) acc[i][j] = fmaf(a[i], b[j], acc[i][j]);
    }
    __syncthreads();
  }

  #pragma unroll
  for (int i = 0; i < 8; ++i) {
    int r = bm + (i < 4 ? ty * 4 + i : 64 + ty * 4 + (i - 4));
    if (r >= M) continue;
    #pragma unroll
    for (int j = 0; j < 8; ++j) {
      int c = bn + (j < 4 ? tx * 4 + j : 64 + tx * 4 + (j - 4));
      if (c >= N) continue;
      C[(size_t)r * N + c] = (_Float16)acc[i][j];
    }
  }
}

// ---------------- launch ----------------

extern "C" void kernel_launch(void* const* d_in, const int* in_sizes, int n_in,
                              void* d_out, int out_size, void* d_ws, size_t ws_size,
                              hipStream_t stream) {
  const float* x  = (const float*)d_in[0];
  const int* src  = (const int*)d_in[1];
  const int* dst  = (const int*)d_in[2];
  const float* W1 = (const float*)d_in[3];
  const float* b1 = (const float*)d_in[4];
  const float* W2 = (const float*)d_in[5];
  const float* b2 = (const float*)d_in[6];
  const float* W3 = (const float*)d_in[7];
  const float* b3 = (const float*)d_in[8];
  const float* W4 = (const float*)d_in[9];
  const float* b4 = (const float*)d_in[10];
  float* out = (float*)d_out;

  const int N = GCN_N, E = GCN_E;

  char* ws = (char*)d_ws;
  size_t off = 0;
  _Float16* h16a = (_Float16*)(ws + off); off += (size_t)N * 512 * 2;  // agg out / GEMM A
  _Float16* h16b = (_Float16*)(ws + off); off += (size_t)N * 512 * 2;  // GEMM out / agg in
  _Float16* x16  = (_Float16*)(ws + off); off += (size_t)N * 256 * 2;
  float* c_src = (float*)(ws + off); off += (size_t)N * 4;
  float* c_dst = (float*)(ws + off); off += (size_t)N * 4;
  int* row_ptr = (int*)(ws + off); off += (size_t)(N + 4) * 4;
  int* csr_src = (int*)(ws + off); off += (size_t)E * 4;
  _Float16* WtH1 = (_Float16*)(ws + off); off += (size_t)512 * 256 * 2;
  _Float16* WtL1 = (_Float16*)(ws + off); off += (size_t)512 * 256 * 2;
  _Float16* WtH2 = (_Float16*)(ws + off); off += (size_t)512 * 512 * 2;
  _Float16* WtL2 = (_Float16*)(ws + off); off += (size_t)512 * 512 * 2;
  _Float16* WtH3 = (_Float16*)(ws + off); off += (size_t)512 * 512 * 2;
  _Float16* WtL3 = (_Float16*)(ws + off); off += (size_t)512 * 512 * 2;
  // transients alias h16a (dead before L1 agg writes h16a)
  int* deg_src = (int*)h16a;
  int* deg_dst = deg_src + N;
  int* cursor  = deg_dst + N;
  // t4 [N][40] fp16 aliases x16 (x16 dead after L1 agg)
  _Float16* t4 = x16;

  hipMemsetAsync(deg_src, 0, (size_t)2 * N * 4, stream);
  hist_kernel<<<(E + 255) / 256, 256, 0, stream>>>(src, dst, deg_src, deg_dst, E);
  cinv_kernel<<<(N + 255) / 256, 256, 0, stream>>>(deg_src, deg_dst, c_src, c_dst, N);
  scan_kernel<<<1, 1024, 0, stream>>>(deg_dst, row_ptr, cursor, N);
  fill_csr_kernel<<<(E + 255) / 256, 256, 0, stream>>>(src, dst, cursor, csr_src, E);

  prep_weight_kernel<<<dim3(16, 8), dim3(32, 8), 0, stream>>>(W1, WtH1, WtL1, 256, 512);
  prep_weight_kernel<<<dim3(16, 16), dim3(32, 8), 0, stream>>>(W2, WtH2, WtL2, 512, 512);
  prep_weight_kernel<<<dim3(16, 16), dim3(32, 8), 0, stream>>>(W3, WtH3, WtL3, 512, 512);

  f32_to_f16_kernel<<<2048, 256, 0, stream>>>(x, x16, (long)N * 256 / 4);

  int gm = (N + 127) / 128;  // 391

  // L1: agg 256-dim (f16x4, 64 thr), GEMM K=256
  agg16_kernel<f16x4, 4, 64><<<N, 64, 0, stream>>>(x16, h16a, row_ptr, csr_src, c_src, c_dst);
  mfma_gemm_kernel<<<dim3(gm, 4), 512, 0, stream>>>(h16a, WtH1, WtL1, b1, h16b, N, 256, 512);
  // L2: agg 512-dim (f16x8, 64 thr = 16B/lane)
  agg16_kernel<f16x8, 8, 64><<<N, 64, 0, stream>>>(h16b, h16a, row_ptr, csr_src, c_src, c_dst);
  mfma_gemm_kernel<<<dim3(gm, 4), 512, 0, stream>>>(h16a, WtH2, WtL2, b2, h16b, N, 512, 512);
  // L3
  agg16_kernel<f16x8, 8, 64><<<N, 64, 0, stream>>>(h16b, h16a, row_ptr, csr_src, c_src, c_dst);
  mfma_gemm_kernel<<<dim3(gm, 4), 512, 0, stream>>>(h16a, WtH3, WtL3, b3, h16b, N, 512, 512);
  // L4
  gemm40_kernel<<<dim3(gm, 1), 256, 0, stream>>>(h16b, W4, t4, N, 512, 40);
  agg40_kernel<<<N, 64, 0, stream>>>(t4, out, row_ptr, csr_src, c_src, c_dst, b4);
}

// Round 12
// 911.625 us; speedup vs baseline: 1.3089x; 1.0552x over previous
//
#include <hip/hip_runtime.h>
#include <hip/hip_bf16.h>

// ---------------------------------------------------------------------------
// GCN forward, 4x GraphConv norm='both'. N=50000, E=800000, 256->512->512->512->40
// R12: R9 numerics (fp16 activations; W = fp16-hi + fp16-lo*4096, 2-term f16
// MFMA, 8-wave GEMM). New: 2-deep gather pipeline in all agg kernels
// (latency-bound fix: VALUBusy 16%, BW 47%, occ 76% => ~1 load in flight);
// parallel 3-kernel scan replaces the serial single-block scan.
// ---------------------------------------------------------------------------

#define GCN_N 50000
#define GCN_E 800000

typedef unsigned short u16;
typedef __attribute__((ext_vector_type(4))) float f32x4;
typedef __attribute__((ext_vector_type(4))) _Float16 f16x4;
typedef __attribute__((ext_vector_type(8))) _Float16 f16x8;

__device__ __forceinline__ void gload_lds16(const void* g, void* l) {
  __builtin_amdgcn_global_load_lds((const __attribute__((address_space(1))) void*)g,
                                   (__attribute__((address_space(3))) void*)l, 16, 0, 0);
}

// ---------------- CSR build ----------------

__global__ void hist_kernel(const int* __restrict__ src, const int* __restrict__ dst,
                            int* __restrict__ deg_src, int* __restrict__ deg_dst, int E) {
  int i = blockIdx.x * blockDim.x + threadIdx.x;
  if (i < E) {
    atomicAdd(&deg_src[src[i]], 1);
    atomicAdd(&deg_dst[dst[i]], 1);
  }
}

__global__ void cinv_kernel(const int* __restrict__ deg_src, const int* __restrict__ deg_dst,
                            float* __restrict__ c_src, float* __restrict__ c_dst, int n) {
  int i = blockIdx.x * blockDim.x + threadIdx.x;
  if (i < n) {
    int ds = deg_src[i];
    int dd = deg_dst[i];
    c_src[i] = ds > 0 ? 1.0f / sqrtf((float)ds) : 0.0f;
    c_dst[i] = dd > 0 ? 1.0f / sqrtf((float)dd) : 0.0f;
  }
}

// 256-thread block inclusive scan (4 waves). lds must hold 4 ints.
__device__ __forceinline__ int block_incl_scan(int v, int* lds) {
  int lane = threadIdx.x & 63;
  int wid = threadIdx.x >> 6;
  int x = v;
  #pragma unroll
  for (int o = 1; o < 64; o <<= 1) {
    int y = __shfl_up(x, o, 64);
    if (lane >= o) x += y;
  }
  if (lane == 63) lds[wid] = x;
  __syncthreads();
  int off = 0;
  #pragma unroll
  for (int w = 0; w < 4; ++w)
    if (w < wid) off += lds[w];
  return x + off;
}

// Pass A: per-256-chunk sums of deg.
__global__ void deg_partial_kernel(const int* __restrict__ deg, int* __restrict__ partials, int n) {
  __shared__ int lds[4];
  int i = blockIdx.x * 256 + threadIdx.x;
  int v = (i < n) ? deg[i] : 0;
  int x = v;
  #pragma unroll
  for (int o = 1; o < 64; o <<= 1) x += __shfl_xor(x, o, 64);
  if ((threadIdx.x & 63) == 0) lds[threadIdx.x >> 6] = x;
  __syncthreads();
  if (threadIdx.x == 0) partials[blockIdx.x] = lds[0] + lds[1] + lds[2] + lds[3];
}

// Pass B: exclusive-scan the nb partials in one block; write row_ptr[n]=total.
__global__ void scan_partials_kernel(int* __restrict__ partials, int* __restrict__ row_ptr,
                                     int nb, int n) {
  __shared__ int lds[4];
  int t = threadIdx.x;
  int v = (t < nb) ? partials[t] : 0;
  int incl = block_incl_scan(v, lds);
  if (t < nb) partials[t] = incl - v;  // exclusive
  if (t == 255) row_ptr[n] = incl;     // total (threads >= nb carry full sum)
}

// Pass C: intra-chunk exclusive scan + chunk offset -> row_ptr, cursor.
__global__ void final_scan_kernel(const int* __restrict__ deg, const int* __restrict__ partials,
                                  int* __restrict__ row_ptr, int* __restrict__ cursor, int n) {
  __shared__ int lds[4];
  int i = blockIdx.x * 256 + threadIdx.x;
  int v = (i < n) ? deg[i] : 0;
  int incl = block_incl_scan(v, lds);
  int excl = incl - v + partials[blockIdx.x];
  if (i < n) {
    row_ptr[i] = excl;
    cursor[i] = excl;
  }
}

__global__ void fill_csr_kernel(const int* __restrict__ src, const int* __restrict__ dst,
                                int* __restrict__ cursor, int* __restrict__ csr_src, int E) {
  int i = blockIdx.x * blockDim.x + threadIdx.x;
  if (i < E) {
    int slot = atomicAdd(&cursor[dst[i]], 1);
    csr_src[slot] = src[i];
  }
}

// ---------------- fp32 -> fp16 convert ----------------

__global__ void f32_to_f16_kernel(const float* __restrict__ in, _Float16* __restrict__ out,
                                  long n4) {
  long i = (long)blockIdx.x * blockDim.x + threadIdx.x;
  long stride = (long)gridDim.x * blockDim.x;
  for (; i < n4; i += stride) {
    float4 v = ((const float4*)in)[i];
    f16x4 h;
    h.x = (_Float16)v.x; h.y = (_Float16)v.y; h.z = (_Float16)v.z; h.w = (_Float16)v.w;
    ((f16x4*)out)[i] = h;
  }
}

// ---------------- aggregation (fp16 in, fp32 accum, fp16 out) ----------------
// One block per dst node; thread t owns vector group t of G.
// 2-deep data pipeline: rows k and k+1 held in registers, k+2's chain issued
// before consuming k -> 2 gathers in flight per wave.
template <typename VT, int NE, int G>
__global__ void agg16_kernel(const _Float16* __restrict__ in, _Float16* __restrict__ out,
                             const int* __restrict__ row_ptr, const int* __restrict__ csr_src,
                             const float* __restrict__ c_src, const float* __restrict__ c_dst) {
  int d = blockIdx.x;
  int t = threadIdx.x;
  if (t >= G) return;
  int beg = row_ptr[d];
  int cnt = row_ptr[d + 1] - beg;
  const VT* inv = (const VT*)in;
  float acc[NE];
  #pragma unroll
  for (int e = 0; e < NE; ++e) acc[e] = 0.f;

  VT vA{}, vB{};
  float cA = 0.f, cB = 0.f;
  if (cnt > 0) { int s = csr_src[beg];     cA = c_src[s]; vA = inv[(size_t)s * G + t]; }
  if (cnt > 1) { int s = csr_src[beg + 1]; cB = c_src[s]; vB = inv[(size_t)s * G + t]; }
  for (int k = 0; k < cnt; ++k) {
    VT vN{};
    float cN = 0.f;
    if (k + 2 < cnt) { int s = csr_src[beg + k + 2]; cN = c_src[s]; vN = inv[(size_t)s * G + t]; }
    #pragma unroll
    for (int e = 0; e < NE; ++e) acc[e] = fmaf(cA, (float)vA[e], acc[e]);
    vA = vB; cA = cB;
    vB = vN; cB = cN;
  }
  float cd = c_dst[d];
  VT o;
  #pragma unroll
  for (int e = 0; e < NE; ++e) o[e] = (_Float16)(acc[e] * cd);
  ((VT*)out)[(size_t)d * G + t] = o;
}

// fp16 in -> fp32 out with bias (final 40-dim aggregation), 2-deep pipeline.
__global__ void agg40_kernel(const _Float16* __restrict__ in, float* __restrict__ out,
                             const int* __restrict__ row_ptr, const int* __restrict__ csr_src,
                             const float* __restrict__ c_src, const float* __restrict__ c_dst,
                             const float* __restrict__ bias) {
  int d = blockIdx.x;
  int t = threadIdx.x;
  if (t >= 10) return;
  int beg = row_ptr[d];
  int cnt = row_ptr[d + 1] - beg;
  const f16x4* in4 = (const f16x4*)in;
  float ax = 0.f, ay = 0.f, az = 0.f, aw = 0.f;

  f16x4 vA{}, vB{};
  float cA = 0.f, cB = 0.f;
  if (cnt > 0) { int s = csr_src[beg];     cA = c_src[s]; vA = in4[(size_t)s * 10 + t]; }
  if (cnt > 1) { int s = csr_src[beg + 1]; cB = c_src[s]; vB = in4[(size_t)s * 10 + t]; }
  for (int k = 0; k < cnt; ++k) {
    f16x4 vN{};
    float cN = 0.f;
    if (k + 2 < cnt) { int s = csr_src[beg + k + 2]; cN = c_src[s]; vN = in4[(size_t)s * 10 + t]; }
    ax = fmaf(cA, (float)vA.x, ax);
    ay = fmaf(cA, (float)vA.y, ay);
    az = fmaf(cA, (float)vA.z, az);
    aw = fmaf(cA, (float)vA.w, aw);
    vA = vB; cA = cB;
    vB = vN; cB = cN;
  }
  float cd = c_dst[d];
  float4 b = ((const float4*)bias)[t];
  float4 o;
  o.x = ax * cd + b.x;
  o.y = ay * cd + b.y;
  o.z = az * cd + b.z;
  o.w = aw * cd + b.w;
  ((float4*)out)[(size_t)d * 10 + t] = o;
}

// ---------------- weight prep: W[K][N] fp32 -> Wt hi/lo fp16 [N][K] ----------------

__global__ void prep_weight_kernel(const float* __restrict__ W, _Float16* __restrict__ th,
                                   _Float16* __restrict__ tl, int K, int N) {
  __shared__ float tile[32][33];
  int bn = blockIdx.x * 32, bk = blockIdx.y * 32;
  int tx = threadIdx.x, ty = threadIdx.y;  // (32, 8)
  #pragma unroll
  for (int i = 0; i < 4; ++i)
    tile[ty + i * 8][tx] = W[(size_t)(bk + ty + i * 8) * N + bn + tx];
  __syncthreads();
  #pragma unroll
  for (int i = 0; i < 4; ++i) {
    float v = tile[tx][ty + i * 8];           // = W[bk+tx][bn+ty+i*8]
    _Float16 h = (_Float16)v;
    _Float16 l = (_Float16)((v - (float)h) * 4096.f);
    size_t o = (size_t)(bn + ty + i * 8) * K + bk + tx;  // Wt[n][k], k coalesced
    th[o] = h;
    tl[o] = l;
  }
}

// ---------------- 2-term fp16 MFMA GEMM, 8 waves ----------------
__global__ __launch_bounds__(512, 4) void mfma_gemm_kernel(
    const _Float16* __restrict__ A,
    const _Float16* __restrict__ Bh, const _Float16* __restrict__ Bl,
    const float* __restrict__ bias, _Float16* __restrict__ C,
    int M, int K, int N) {
  __shared__ _Float16 sA[128 * 32], sBh[128 * 32], sBl[128 * 32];
  int t = threadIdx.x;
  int lane = t & 63, wid = t >> 6;
  int wr = wid >> 2, wc = wid & 3;        // 2 x 4 wave grid
  int lr = lane & 15, ko = lane >> 4;
  int swz = (lr & 3) ^ ((lr >> 2) & 3);
  int koff = ((ko ^ swz) << 3);           // fp16 units within a 32-elem row
  int bm = blockIdx.x * 128, bn = blockIdx.y * 128;

  f32x4 acch[4][2] = {};
  f32x4 accl[4][2] = {};

  int aoff[4], boff[2];
  #pragma unroll
  for (int i = 0; i < 4; ++i) aoff[i] = (wr * 64 + i * 16 + lr) * 32 + koff;
  #pragma unroll
  for (int j = 0; j < 2; ++j) boff[j] = (wc * 32 + j * 16 + lr) * 32 + koff;

  int srow = t >> 2;
  int sc = (t & 3) ^ ((srow & 3) ^ ((srow >> 2) & 3));
  int ldst = wid * 512;  // fp16 units; wave-uniform base, lane*16B implicit
  int gra = bm + srow;
  if (gra >= M) gra = M - 1;
  size_t gabase = (size_t)gra * K + sc * 8;
  size_t gbbase = (size_t)(bn + srow) * K + sc * 8;  // N%128==0 for these layers

  for (int k0 = 0; k0 < K; k0 += 32) {
    gload_lds16(A + gabase + k0, sA + ldst);
    gload_lds16(Bh + gbbase + k0, sBh + ldst);
    gload_lds16(Bl + gbbase + k0, sBl + ldst);
    __syncthreads();
    f16x8 a[4], bh[2], bl[2];
    #pragma unroll
    for (int i = 0; i < 4; ++i) a[i] = *(const f16x8*)(sA + aoff[i]);
    #pragma unroll
    for (int j = 0; j < 2; ++j) {
      bh[j] = *(const f16x8*)(sBh + boff[j]);
      bl[j] = *(const f16x8*)(sBl + boff[j]);
    }
    #pragma unroll
    for (int i = 0; i < 4; ++i)
      #pragma unroll
      for (int j = 0; j < 2; ++j) {
        acch[i][j] = __builtin_amdgcn_mfma_f32_16x16x32_f16(a[i], bh[j], acch[i][j], 0, 0, 0);
        accl[i][j] = __builtin_amdgcn_mfma_f32_16x16x32_f16(a[i], bl[j], accl[i][j], 0, 0, 0);
      }
    __syncthreads();
  }

  const float inv_s = 1.0f / 4096.0f;
  int r0 = (lane >> 4) << 2;
  #pragma unroll
  for (int i = 0; i < 4; ++i) {
    #pragma unroll
    for (int j = 0; j < 2; ++j) {
      int col = bn + wc * 32 + j * 16 + lr;
      float bv = bias[col];
      #pragma unroll
      for (int r = 0; r < 4; ++r) {
        int row = bm + wr * 64 + i * 16 + r0 + r;
        if (row < M) {
          float v = acch[i][j][r] + accl[i][j][r] * inv_s + bv;
          v = v > 0.f ? v : 0.f;
          C[(size_t)row * N + col] = (_Float16)v;
        }
      }
    }
  }
}

// ---------------- fp32 VALU GEMM, fp16 A and C (layer 4, N=40) ----------------

__global__ __launch_bounds__(256) void gemm40_kernel(const _Float16* __restrict__ A,
                                                     const float* __restrict__ W,
                                                     _Float16* __restrict__ C,
                                                     int M, int K, int N) {
  __shared__ float As[16][128 + 4];
  __shared__ float Bs[16][128 + 4];
  int tid = threadIdx.x;
  int tx = tid & 15;
  int ty = tid >> 4;
  int bm = blockIdx.x * 128;
  int bn = blockIdx.y * 128;

  float acc[8][8];
  #pragma unroll
  for (int i = 0; i < 8; ++i)
    #pragma unroll
    for (int j = 0; j < 8; ++j) acc[i][j] = 0.f;

  int ar = tid >> 2;
  int akq = (tid & 3) << 2;
  int bkk = tid >> 4;
  int bcq = (tid & 15) << 2;

  for (int k0 = 0; k0 < K; k0 += 16) {
    #pragma unroll
    for (int half = 0; half < 2; ++half) {
      int r = ar + half * 64;
      int grow = bm + r;
      float4 v = make_float4(0.f, 0.f, 0.f, 0.f);
      if (grow < M) {
        f16x4 hv = *(const f16x4*)&A[(size_t)grow * K + k0 + akq];
        v = make_float4((float)hv.x, (float)hv.y, (float)hv.z, (float)hv.w);
      }
      As[akq + 0][r] = v.x;
      As[akq + 1][r] = v.y;
      As[akq + 2][r] = v.z;
      As[akq + 3][r] = v.w;
    }
    #pragma unroll
    for (int half = 0; half < 2; ++half) {
      int c = bcq + half * 64;
      int gc = bn + c;
      float4 v = make_float4(0.f, 0.f, 0.f, 0.f);
      if (gc + 3 < N) v = *(const float4*)&W[(size_t)(k0 + bkk) * N + gc];
      *(float4*)&Bs[bkk][c] = v;
    }
    __syncthreads();
    #pragma unroll
    for (int kk = 0; kk < 16; ++kk) {
      float4 a0 = *(const float4*)&As[kk][ty * 4];
      float4 a1 = *(const float4*)&As[kk][ty * 4 + 64];
      float4 b0 = *(const float4*)&Bs[kk][tx * 4];
      float4 b1 = *(const float4*)&Bs[kk][tx * 4 + 64];
      float a[8] = {a0.x, a0.y, a0.z, a0.w, a1.x, a1.y, a1.z, a1.w};
      float b[8] = {b0.x, b0.y, b0.z, b0.w, b1.x, b1.y, b1.z, b1.w};
      #pragma unroll
      for (int i = 0; i < 8; ++i)
        #pragma unroll
        for (int j = 0; j < 8; ++j) acc[i][j] = fmaf(a[i], b[j], acc[i][j]);
    }
    __syncthreads();
  }

  #pragma unroll
  for (int i = 0; i < 8; ++i) {
    int r = bm + (i < 4 ? ty * 4 + i : 64 + ty * 4 + (i - 4));
    if (r >= M) continue;
    #pragma unroll
    for (int j = 0; j < 8; ++j) {
      int c = bn + (j < 4 ? tx * 4 + j : 64 + tx * 4 + (j - 4));
      if (c >= N) continue;
      C[(size_t)r * N + c] = (_Float16)acc[i][j];
    }
  }
}

// ---------------- launch ----------------

extern "C" void kernel_launch(void* const* d_in, const int* in_sizes, int n_in,
                              void* d_out, int out_size, void* d_ws, size_t ws_size,
                              hipStream_t stream) {
  const float* x  = (const float*)d_in[0];
  const int* src  = (const int*)d_in[1];
  const int* dst  = (const int*)d_in[2];
  const float* W1 = (const float*)d_in[3];
  const float* b1 = (const float*)d_in[4];
  const float* W2 = (const float*)d_in[5];
  const float* b2 = (const float*)d_in[6];
  const float* W3 = (const float*)d_in[7];
  const float* b3 = (const float*)d_in[8];
  const float* W4 = (const float*)d_in[9];
  const float* b4 = (const float*)d_in[10];
  float* out = (float*)d_out;

  const int N = GCN_N, E = GCN_E;
  const int NB = (N + 255) / 256;  // 196 scan chunks

  char* ws = (char*)d_ws;
  size_t off = 0;
  _Float16* h16a = (_Float16*)(ws + off); off += (size_t)N * 512 * 2;  // agg out / GEMM A
  _Float16* h16b = (_Float16*)(ws + off); off += (size_t)N * 512 * 2;  // GEMM out / agg in
  _Float16* x16  = (_Float16*)(ws + off); off += (size_t)N * 256 * 2;
  float* c_src = (float*)(ws + off); off += (size_t)N * 4;
  float* c_dst = (float*)(ws + off); off += (size_t)N * 4;
  int* row_ptr = (int*)(ws + off); off += (size_t)(N + 4) * 4;
  int* csr_src = (int*)(ws + off); off += (size_t)E * 4;
  int* partials = (int*)(ws + off); off += 256 * 4;
  _Float16* WtH1 = (_Float16*)(ws + off); off += (size_t)512 * 256 * 2;
  _Float16* WtL1 = (_Float16*)(ws + off); off += (size_t)512 * 256 * 2;
  _Float16* WtH2 = (_Float16*)(ws + off); off += (size_t)512 * 512 * 2;
  _Float16* WtL2 = (_Float16*)(ws + off); off += (size_t)512 * 512 * 2;
  _Float16* WtH3 = (_Float16*)(ws + off); off += (size_t)512 * 512 * 2;
  _Float16* WtL3 = (_Float16*)(ws + off); off += (size_t)512 * 512 * 2;
  // transients alias h16a (dead before L1 agg writes h16a)
  int* deg_src = (int*)h16a;
  int* deg_dst = deg_src + N;
  int* cursor  = deg_dst + N;
  // t4 [N][40] fp16 aliases x16 (x16 dead after L1 agg)
  _Float16* t4 = x16;

  hipMemsetAsync(deg_src, 0, (size_t)2 * N * 4, stream);
  hist_kernel<<<(E + 255) / 256, 256, 0, stream>>>(src, dst, deg_src, deg_dst, E);
  cinv_kernel<<<(N + 255) / 256, 256, 0, stream>>>(deg_src, deg_dst, c_src, c_dst, N);
  deg_partial_kernel<<<NB, 256, 0, stream>>>(deg_dst, partials, N);
  scan_partials_kernel<<<1, 256, 0, stream>>>(partials, row_ptr, NB, N);
  final_scan_kernel<<<NB, 256, 0, stream>>>(deg_dst, partials, row_ptr, cursor, N);
  fill_csr_kernel<<<(E + 255) / 256, 256, 0, stream>>>(src, dst, cursor, csr_src, E);

  prep_weight_kernel<<<dim3(16, 8), dim3(32, 8), 0, stream>>>(W1, WtH1, WtL1, 256, 512);
  prep_weight_kernel<<<dim3(16, 16), dim3(32, 8), 0, stream>>>(W2, WtH2, WtL2, 512, 512);
  prep_weight_kernel<<<dim3(16, 16), dim3(32, 8), 0, stream>>>(W3, WtH3, WtL3, 512, 512);

  f32_to_f16_kernel<<<2048, 256, 0, stream>>>(x, x16, (long)N * 256 / 4);

  int gm = (N + 127) / 128;  // 391

  // L1: agg 256-dim (f16x4, 64 thr), GEMM K=256
  agg16_kernel<f16x4, 4, 64><<<N, 64, 0, stream>>>(x16, h16a, row_ptr, csr_src, c_src, c_dst);
  mfma_gemm_kernel<<<dim3(gm, 4), 512, 0, stream>>>(h16a, WtH1, WtL1, b1, h16b, N, 256, 512);
  // L2: agg 512-dim (f16x8, 64 thr = 16B/lane)
  agg16_kernel<f16x8, 8, 64><<<N, 64, 0, stream>>>(h16b, h16a, row_ptr, csr_src, c_src, c_dst);
  mfma_gemm_kernel<<<dim3(gm, 4), 512, 0, stream>>>(h16a, WtH2, WtL2, b2, h16b, N, 512, 512);
  // L3
  agg16_kernel<f16x8, 8, 64><<<N, 64, 0, stream>>>(h16b, h16a, row_ptr, csr_src, c_src, c_dst);
  mfma_gemm_kernel<<<dim3(gm, 4), 512, 0, stream>>>(h16a, WtH3, WtL3, b3, h16b, N, 512, 512);
  // L4
  gemm40_kernel<<<dim3(gm, 1), 256, 0, stream>>>(h16b, W4, t4, N, 512, 40);
  agg40_kernel<<<N, 64, 0, stream>>>(t4, out, row_ptr, csr_src, c_src, c_dst, b4);
}

// Round 13
// 910.027 us; speedup vs baseline: 1.3112x; 1.0018x over previous
//
#include <hip/hip_runtime.h>
#include <hip/hip_bf16.h>

// ---------------------------------------------------------------------------
// GCN forward, 4x GraphConv norm='both'. N=50000, E=800000, 256->512->512->512->40
// R13: R12 numerics (fp16 activations; W = fp16-hi + fp16-lo*4096, 2-term f16
// MFMA, 8-wave GEMM). New: (a) GEMM BK=64 (two stacked BK=32 halves, half the
// barriers); (b) non-temporal stores for agg outputs (LLC-pollution test).
// ---------------------------------------------------------------------------

#define GCN_N 50000
#define GCN_E 800000

typedef unsigned short u16;
typedef __attribute__((ext_vector_type(4))) float f32x4;
typedef __attribute__((ext_vector_type(4))) _Float16 f16x4;
typedef __attribute__((ext_vector_type(8))) _Float16 f16x8;

__device__ __forceinline__ void gload_lds16(const void* g, void* l) {
  __builtin_amdgcn_global_load_lds((const __attribute__((address_space(1))) void*)g,
                                   (__attribute__((address_space(3))) void*)l, 16, 0, 0);
}

// ---------------- CSR build ----------------

__global__ void hist_kernel(const int* __restrict__ src, const int* __restrict__ dst,
                            int* __restrict__ deg_src, int* __restrict__ deg_dst, int E) {
  int i = blockIdx.x * blockDim.x + threadIdx.x;
  if (i < E) {
    atomicAdd(&deg_src[src[i]], 1);
    atomicAdd(&deg_dst[dst[i]], 1);
  }
}

__global__ void cinv_kernel(const int* __restrict__ deg_src, const int* __restrict__ deg_dst,
                            float* __restrict__ c_src, float* __restrict__ c_dst, int n) {
  int i = blockIdx.x * blockDim.x + threadIdx.x;
  if (i < n) {
    int ds = deg_src[i];
    int dd = deg_dst[i];
    c_src[i] = ds > 0 ? 1.0f / sqrtf((float)ds) : 0.0f;
    c_dst[i] = dd > 0 ? 1.0f / sqrtf((float)dd) : 0.0f;
  }
}

// 256-thread block inclusive scan (4 waves). lds must hold 4 ints.
__device__ __forceinline__ int block_incl_scan(int v, int* lds) {
  int lane = threadIdx.x & 63;
  int wid = threadIdx.x >> 6;
  int x = v;
  #pragma unroll
  for (int o = 1; o < 64; o <<= 1) {
    int y = __shfl_up(x, o, 64);
    if (lane >= o) x += y;
  }
  if (lane == 63) lds[wid] = x;
  __syncthreads();
  int off = 0;
  #pragma unroll
  for (int w = 0; w < 4; ++w)
    if (w < wid) off += lds[w];
  return x + off;
}

__global__ void deg_partial_kernel(const int* __restrict__ deg, int* __restrict__ partials, int n) {
  __shared__ int lds[4];
  int i = blockIdx.x * 256 + threadIdx.x;
  int v = (i < n) ? deg[i] : 0;
  int x = v;
  #pragma unroll
  for (int o = 1; o < 64; o <<= 1) x += __shfl_xor(x, o, 64);
  if ((threadIdx.x & 63) == 0) lds[threadIdx.x >> 6] = x;
  __syncthreads();
  if (threadIdx.x == 0) partials[blockIdx.x] = lds[0] + lds[1] + lds[2] + lds[3];
}

__global__ void scan_partials_kernel(int* __restrict__ partials, int* __restrict__ row_ptr,
                                     int nb, int n) {
  __shared__ int lds[4];
  int t = threadIdx.x;
  int v = (t < nb) ? partials[t] : 0;
  int incl = block_incl_scan(v, lds);
  if (t < nb) partials[t] = incl - v;  // exclusive
  if (t == 255) row_ptr[n] = incl;     // total
}

__global__ void final_scan_kernel(const int* __restrict__ deg, const int* __restrict__ partials,
                                  int* __restrict__ row_ptr, int* __restrict__ cursor, int n) {
  __shared__ int lds[4];
  int i = blockIdx.x * 256 + threadIdx.x;
  int v = (i < n) ? deg[i] : 0;
  int incl = block_incl_scan(v, lds);
  int excl = incl - v + partials[blockIdx.x];
  if (i < n) {
    row_ptr[i] = excl;
    cursor[i] = excl;
  }
}

__global__ void fill_csr_kernel(const int* __restrict__ src, const int* __restrict__ dst,
                                int* __restrict__ cursor, int* __restrict__ csr_src, int E) {
  int i = blockIdx.x * blockDim.x + threadIdx.x;
  if (i < E) {
    int slot = atomicAdd(&cursor[dst[i]], 1);
    csr_src[slot] = src[i];
  }
}

// ---------------- fp32 -> fp16 convert ----------------

__global__ void f32_to_f16_kernel(const float* __restrict__ in, _Float16* __restrict__ out,
                                  long n4) {
  long i = (long)blockIdx.x * blockDim.x + threadIdx.x;
  long stride = (long)gridDim.x * blockDim.x;
  for (; i < n4; i += stride) {
    float4 v = ((const float4*)in)[i];
    f16x4 h;
    h.x = (_Float16)v.x; h.y = (_Float16)v.y; h.z = (_Float16)v.z; h.w = (_Float16)v.w;
    ((f16x4*)out)[i] = h;
  }
}

// ---------------- aggregation (fp16 in, fp32 accum, fp16 out) ----------------
// 2-deep gather pipeline; non-temporal output store (don't pollute LLC with
// the 50 MB output stream while the gather source needs residency).
template <typename VT, int NE, int G>
__global__ void agg16_kernel(const _Float16* __restrict__ in, _Float16* __restrict__ out,
                             const int* __restrict__ row_ptr, const int* __restrict__ csr_src,
                             const float* __restrict__ c_src, const float* __restrict__ c_dst) {
  int d = blockIdx.x;
  int t = threadIdx.x;
  if (t >= G) return;
  int beg = row_ptr[d];
  int cnt = row_ptr[d + 1] - beg;
  const VT* inv = (const VT*)in;
  float acc[NE];
  #pragma unroll
  for (int e = 0; e < NE; ++e) acc[e] = 0.f;

  VT vA{}, vB{};
  float cA = 0.f, cB = 0.f;
  if (cnt > 0) { int s = csr_src[beg];     cA = c_src[s]; vA = inv[(size_t)s * G + t]; }
  if (cnt > 1) { int s = csr_src[beg + 1]; cB = c_src[s]; vB = inv[(size_t)s * G + t]; }
  for (int k = 0; k < cnt; ++k) {
    VT vN{};
    float cN = 0.f;
    if (k + 2 < cnt) { int s = csr_src[beg + k + 2]; cN = c_src[s]; vN = inv[(size_t)s * G + t]; }
    #pragma unroll
    for (int e = 0; e < NE; ++e) acc[e] = fmaf(cA, (float)vA[e], acc[e]);
    vA = vB; cA = cB;
    vB = vN; cB = cN;
  }
  float cd = c_dst[d];
  VT o;
  #pragma unroll
  for (int e = 0; e < NE; ++e) o[e] = (_Float16)(acc[e] * cd);
  __builtin_nontemporal_store(o, (VT*)out + (size_t)d * G + t);
}

// fp16 in -> fp32 out with bias (final 40-dim aggregation), 2-deep pipeline.
__global__ void agg40_kernel(const _Float16* __restrict__ in, float* __restrict__ out,
                             const int* __restrict__ row_ptr, const int* __restrict__ csr_src,
                             const float* __restrict__ c_src, const float* __restrict__ c_dst,
                             const float* __restrict__ bias) {
  int d = blockIdx.x;
  int t = threadIdx.x;
  if (t >= 10) return;
  int beg = row_ptr[d];
  int cnt = row_ptr[d + 1] - beg;
  const f16x4* in4 = (const f16x4*)in;
  float ax = 0.f, ay = 0.f, az = 0.f, aw = 0.f;

  f16x4 vA{}, vB{};
  float cA = 0.f, cB = 0.f;
  if (cnt > 0) { int s = csr_src[beg];     cA = c_src[s]; vA = in4[(size_t)s * 10 + t]; }
  if (cnt > 1) { int s = csr_src[beg + 1]; cB = c_src[s]; vB = in4[(size_t)s * 10 + t]; }
  for (int k = 0; k < cnt; ++k) {
    f16x4 vN{};
    float cN = 0.f;
    if (k + 2 < cnt) { int s = csr_src[beg + k + 2]; cN = c_src[s]; vN = in4[(size_t)s * 10 + t]; }
    ax = fmaf(cA, (float)vA.x, ax);
    ay = fmaf(cA, (float)vA.y, ay);
    az = fmaf(cA, (float)vA.z, az);
    aw = fmaf(cA, (float)vA.w, aw);
    vA = vB; cA = cB;
    vB = vN; cB = cN;
  }
  float cd = c_dst[d];
  float4 b = ((const float4*)bias)[t];
  f32x4 o;
  o[0] = ax * cd + b.x;
  o[1] = ay * cd + b.y;
  o[2] = az * cd + b.z;
  o[3] = aw * cd + b.w;
  __builtin_nontemporal_store(o, (f32x4*)out + (size_t)d * 10 + t);
}

// ---------------- weight prep: W[K][N] fp32 -> Wt hi/lo fp16 [N][K] ----------------

__global__ void prep_weight_kernel(const float* __restrict__ W, _Float16* __restrict__ th,
                                   _Float16* __restrict__ tl, int K, int N) {
  __shared__ float tile[32][33];
  int bn = blockIdx.x * 32, bk = blockIdx.y * 32;
  int tx = threadIdx.x, ty = threadIdx.y;  // (32, 8)
  #pragma unroll
  for (int i = 0; i < 4; ++i)
    tile[ty + i * 8][tx] = W[(size_t)(bk + ty + i * 8) * N + bn + tx];
  __syncthreads();
  #pragma unroll
  for (int i = 0; i < 4; ++i) {
    float v = tile[tx][ty + i * 8];           // = W[bk+tx][bn+ty+i*8]
    _Float16 h = (_Float16)v;
    _Float16 l = (_Float16)((v - (float)h) * 4096.f);
    size_t o = (size_t)(bn + ty + i * 8) * K + bk + tx;  // Wt[n][k], k coalesced
    th[o] = h;
    tl[o] = l;
  }
}

// ---------------- 2-term fp16 MFMA GEMM, 8 waves, BK=64 ----------------
// C16[M][N] = relu( A[M][K](fp16) * (Bh + Bl/4096)^T[N][K] + bias )
// 128x128 tile, BK=64 as two stacked BK=32 halves (same swizzle per half),
// 512 thr = 8 waves (2Mx4N), 4x2 frags/wave, dual acc = 64 regs/thread.
__global__ __launch_bounds__(512, 4) void mfma_gemm_kernel(
    const _Float16* __restrict__ A,
    const _Float16* __restrict__ Bh, const _Float16* __restrict__ Bl,
    const float* __restrict__ bias, _Float16* __restrict__ C,
    int M, int K, int N) {
  __shared__ _Float16 sA[2 * 128 * 32], sBh[2 * 128 * 32], sBl[2 * 128 * 32];
  int t = threadIdx.x;
  int lane = t & 63, wid = t >> 6;
  int wr = wid >> 2, wc = wid & 3;        // 2 x 4 wave grid
  int lr = lane & 15, ko = lane >> 4;
  int swz = (lr & 3) ^ ((lr >> 2) & 3);
  int koff = ((ko ^ swz) << 3);           // fp16 units within a 32-elem row
  int bm = blockIdx.x * 128, bn = blockIdx.y * 128;

  f32x4 acch[4][2] = {};
  f32x4 accl[4][2] = {};

  int aoff[4], boff[2];
  #pragma unroll
  for (int i = 0; i < 4; ++i) aoff[i] = (wr * 64 + i * 16 + lr) * 32 + koff;
  #pragma unroll
  for (int j = 0; j < 2; ++j) boff[j] = (wc * 32 + j * 16 + lr) * 32 + koff;

  int srow = t >> 2;
  int sc = (t & 3) ^ ((srow & 3) ^ ((srow >> 2) & 3));
  int ldst = wid * 512;  // fp16 units within an 8K-half; wave-uniform base
  int gra = bm + srow;
  if (gra >= M) gra = M - 1;
  size_t gabase = (size_t)gra * K + sc * 8;
  size_t gbbase = (size_t)(bn + srow) * K + sc * 8;  // N%128==0 for these layers

  for (int k0 = 0; k0 < K; k0 += 64) {
    #pragma unroll
    for (int ks = 0; ks < 2; ++ks) {
      int gofs = k0 + ks * 32;
      int lofs = ks * 4096 + ldst;
      gload_lds16(A + gabase + gofs, sA + lofs);
      gload_lds16(Bh + gbbase + gofs, sBh + lofs);
      gload_lds16(Bl + gbbase + gofs, sBl + lofs);
    }
    __syncthreads();
    #pragma unroll
    for (int ks = 0; ks < 2; ++ks) {
      int lofs = ks * 4096;
      f16x8 a[4], bh[2], bl[2];
      #pragma unroll
      for (int i = 0; i < 4; ++i) a[i] = *(const f16x8*)(sA + lofs + aoff[i]);
      #pragma unroll
      for (int j = 0; j < 2; ++j) {
        bh[j] = *(const f16x8*)(sBh + lofs + boff[j]);
        bl[j] = *(const f16x8*)(sBl + lofs + boff[j]);
      }
      #pragma unroll
      for (int i = 0; i < 4; ++i)
        #pragma unroll
        for (int j = 0; j < 2; ++j) {
          acch[i][j] = __builtin_amdgcn_mfma_f32_16x16x32_f16(a[i], bh[j], acch[i][j], 0, 0, 0);
          accl[i][j] = __builtin_amdgcn_mfma_f32_16x16x32_f16(a[i], bl[j], accl[i][j], 0, 0, 0);
        }
    }
    __syncthreads();
  }

  const float inv_s = 1.0f / 4096.0f;
  int r0 = (lane >> 4) << 2;
  #pragma unroll
  for (int i = 0; i < 4; ++i) {
    #pragma unroll
    for (int j = 0; j < 2; ++j) {
      int col = bn + wc * 32 + j * 16 + lr;
      float bv = bias[col];
      #pragma unroll
      for (int r = 0; r < 4; ++r) {
        int row = bm + wr * 64 + i * 16 + r0 + r;
        if (row < M) {
          float v = acch[i][j][r] + accl[i][j][r] * inv_s + bv;
          v = v > 0.f ? v : 0.f;
          C[(size_t)row * N + col] = (_Float16)v;  // cached: next agg gathers this
        }
      }
    }
  }
}

// ---------------- fp32 VALU GEMM, fp16 A and C (layer 4, N=40) ----------------

__global__ __launch_bounds__(256) void gemm40_kernel(const _Float16* __restrict__ A,
                                                     const float* __restrict__ W,
                                                     _Float16* __restrict__ C,
                                                     int M, int K, int N) {
  __shared__ float As[16][128 + 4];
  __shared__ float Bs[16][128 + 4];
  int tid = threadIdx.x;
  int tx = tid & 15;
  int ty = tid >> 4;
  int bm = blockIdx.x * 128;
  int bn = blockIdx.y * 128;

  float acc[8][8];
  #pragma unroll
  for (int i = 0; i < 8; ++i)
    #pragma unroll
    for (int j = 0; j < 8; ++j) acc[i][j] = 0.f;

  int ar = tid >> 2;
  int akq = (tid & 3) << 2;
  int bkk = tid >> 4;
  int bcq = (tid & 15) << 2;

  for (int k0 = 0; k0 < K; k0 += 16) {
    #pragma unroll
    for (int half = 0; half < 2; ++half) {
      int r = ar + half * 64;
      int grow = bm + r;
      float4 v = make_float4(0.f, 0.f, 0.f, 0.f);
      if (grow < M) {
        f16x4 hv = *(const f16x4*)&A[(size_t)grow * K + k0 + akq];
        v = make_float4((float)hv.x, (float)hv.y, (float)hv.z, (float)hv.w);
      }
      As[akq + 0][r] = v.x;
      As[akq + 1][r] = v.y;
      As[akq + 2][r] = v.z;
      As[akq + 3][r] = v.w;
    }
    #pragma unroll
    for (int half = 0; half < 2; ++half) {
      int c = bcq + half * 64;
      int gc = bn + c;
      float4 v = make_float4(0.f, 0.f, 0.f, 0.f);
      if (gc + 3 < N) v = *(const float4*)&W[(size_t)(k0 + bkk) * N + gc];
      *(float4*)&Bs[bkk][c] = v;
    }
    __syncthreads();
    #pragma unroll
    for (int kk = 0; kk < 16; ++kk) {
      float4 a0 = *(const float4*)&As[kk][ty * 4];
      float4 a1 = *(const float4*)&As[kk][ty * 4 + 64];
      float4 b0 = *(const float4*)&Bs[kk][tx * 4];
      float4 b1 = *(const float4*)&Bs[kk][tx * 4 + 64];
      float a[8] = {a0.x, a0.y, a0.z, a0.w, a1.x, a1.y, a1.z, a1.w};
      float b[8] = {b0.x, b0.y, b0.z, b0.w, b1.x, b1.y, b1.z, b1.w};
      #pragma unroll
      for (int i = 0; i < 8; ++i)
        #pragma unroll
        for (int j = 0; j < 8; ++j) acc[i][j] = fmaf(a[i], b[j], acc[i][j]);
    }
    __syncthreads();
  }

  #pragma unroll
  for (int i = 0; i < 8; ++i) {
    int r = bm + (i < 4 ? ty * 4 + i : 64 + ty * 4 + (i - 4));
    if (r >= M) continue;
    #pragma unroll
    for (int j = 0; j < 8; ++j) {
      int c = bn + (j < 4 ? tx * 4 + j : 64 + tx * 4 + (j - 4));
      if (c >= N) continue;
      C[(size_t)r * N + c] = (_Float16)acc[i][j];
    }
  }
}

// ---------------- launch ----------------

extern "C" void kernel_launch(void* const* d_in, const int* in_sizes, int n_in,
                              void* d_out, int out_size, void* d_ws, size_t ws_size,
                              hipStream_t stream) {
  const float* x  = (const float*)d_in[0];
  const int* src  = (const int*)d_in[1];
  const int* dst  = (const int*)d_in[2];
  const float* W1 = (const float*)d_in[3];
  const float* b1 = (const float*)d_in[4];
  const float* W2 = (const float*)d_in[5];
  const float* b2 = (const float*)d_in[6];
  const float* W3 = (const float*)d_in[7];
  const float* b3 = (const float*)d_in[8];
  const float* W4 = (const float*)d_in[9];
  const float* b4 = (const float*)d_in[10];
  float* out = (float*)d_out;

  const int N = GCN_N, E = GCN_E;
  const int NB = (N + 255) / 256;  // 196 scan chunks

  char* ws = (char*)d_ws;
  size_t off = 0;
  _Float16* h16a = (_Float16*)(ws + off); off += (size_t)N * 512 * 2;  // agg out / GEMM A
  _Float16* h16b = (_Float16*)(ws + off); off += (size_t)N * 512 * 2;  // GEMM out / agg in
  _Float16* x16  = (_Float16*)(ws + off); off += (size_t)N * 256 * 2;
  float* c_src = (float*)(ws + off); off += (size_t)N * 4;
  float* c_dst = (float*)(ws + off); off += (size_t)N * 4;
  int* row_ptr = (int*)(ws + off); off += (size_t)(N + 4) * 4;
  int* csr_src = (int*)(ws + off); off += (size_t)E * 4;
  int* partials = (int*)(ws + off); off += 256 * 4;
  _Float16* WtH1 = (_Float16*)(ws + off); off += (size_t)512 * 256 * 2;
  _Float16* WtL1 = (_Float16*)(ws + off); off += (size_t)512 * 256 * 2;
  _Float16* WtH2 = (_Float16*)(ws + off); off += (size_t)512 * 512 * 2;
  _Float16* WtL2 = (_Float16*)(ws + off); off += (size_t)512 * 512 * 2;
  _Float16* WtH3 = (_Float16*)(ws + off); off += (size_t)512 * 512 * 2;
  _Float16* WtL3 = (_Float16*)(ws + off); off += (size_t)512 * 512 * 2;
  // transients alias h16a (dead before L1 agg writes h16a)
  int* deg_src = (int*)h16a;
  int* deg_dst = deg_src + N;
  int* cursor  = deg_dst + N;
  // t4 [N][40] fp16 aliases x16 (x16 dead after L1 agg)
  _Float16* t4 = x16;

  hipMemsetAsync(deg_src, 0, (size_t)2 * N * 4, stream);
  hist_kernel<<<(E + 255) / 256, 256, 0, stream>>>(src, dst, deg_src, deg_dst, E);
  cinv_kernel<<<(N + 255) / 256, 256, 0, stream>>>(deg_src, deg_dst, c_src, c_dst, N);
  deg_partial_kernel<<<NB, 256, 0, stream>>>(deg_dst, partials, N);
  scan_partials_kernel<<<1, 256, 0, stream>>>(partials, row_ptr, NB, N);
  final_scan_kernel<<<NB, 256, 0, stream>>>(deg_dst, partials, row_ptr, cursor, N);
  fill_csr_kernel<<<(E + 255) / 256, 256, 0, stream>>>(src, dst, cursor, csr_src, E);

  prep_weight_kernel<<<dim3(16, 8), dim3(32, 8), 0, stream>>>(W1, WtH1, WtL1, 256, 512);
  prep_weight_kernel<<<dim3(16, 16), dim3(32, 8), 0, stream>>>(W2, WtH2, WtL2, 512, 512);
  prep_weight_kernel<<<dim3(16, 16), dim3(32, 8), 0, stream>>>(W3, WtH3, WtL3, 512, 512);

  f32_to_f16_kernel<<<2048, 256, 0, stream>>>(x, x16, (long)N * 256 / 4);

  int gm = (N + 127) / 128;  // 391

  // L1: agg 256-dim (f16x4, 64 thr), GEMM K=256
  agg16_kernel<f16x4, 4, 64><<<N, 64, 0, stream>>>(x16, h16a, row_ptr, csr_src, c_src, c_dst);
  mfma_gemm_kernel<<<dim3(gm, 4), 512, 0, stream>>>(h16a, WtH1, WtL1, b1, h16b, N, 256, 512);
  // L2: agg 512-dim (f16x8, 64 thr = 16B/lane)
  agg16_kernel<f16x8, 8, 64><<<N, 64, 0, stream>>>(h16b, h16a, row_ptr, csr_src, c_src, c_dst);
  mfma_gemm_kernel<<<dim3(gm, 4), 512, 0, stream>>>(h16a, WtH2, WtL2, b2, h16b, N, 512, 512);
  // L3
  agg16_kernel<f16x8, 8, 64><<<N, 64, 0, stream>>>(h16b, h16a, row_ptr, csr_src, c_src, c_dst);
  mfma_gemm_kernel<<<dim3(gm, 4), 512, 0, stream>>>(h16a, WtH3, WtL3, b3, h16b, N, 512, 512);
  // L4
  gemm40_kernel<<<dim3(gm, 1), 256, 0, stream>>>(h16b, W4, t4, N, 512, 40);
  agg40_kernel<<<N, 64, 0, stream>>>(t4, out, row_ptr, csr_src, c_src, c_dst, b4);
}

// Round 15
// 830.962 us; speedup vs baseline: 1.4360x; 1.0951x over previous
//
#include <hip/hip_runtime.h>
#include <hip/hip_bf16.h>

// ---------------------------------------------------------------------------
// GCN forward, 4x GraphConv norm='both'. N=50000, E=800000, 256->512->512->512->40
// R14 (re-run; previous bench was a broker capacity timeout): single-term fp16
// MFMA GEMM (W = fp16 RNE; dropped W_lo — its 2^-11 contribution is same scale
// as the fp16-h quantization already carried; predicted absmax ~2e-3 < 3.75e-3).
// Halves MFMA work + staging. Aggregation unchanged (fabric roofline).
// ---------------------------------------------------------------------------

#define GCN_N 50000
#define GCN_E 800000

typedef unsigned short u16;
typedef __attribute__((ext_vector_type(4))) float f32x4;
typedef __attribute__((ext_vector_type(4))) _Float16 f16x4;
typedef __attribute__((ext_vector_type(8))) _Float16 f16x8;

__device__ __forceinline__ void gload_lds16(const void* g, void* l) {
  __builtin_amdgcn_global_load_lds((const __attribute__((address_space(1))) void*)g,
                                   (__attribute__((address_space(3))) void*)l, 16, 0, 0);
}

// ---------------- CSR build ----------------

__global__ void hist_kernel(const int* __restrict__ src, const int* __restrict__ dst,
                            int* __restrict__ deg_src, int* __restrict__ deg_dst, int E) {
  int i = blockIdx.x * blockDim.x + threadIdx.x;
  if (i < E) {
    atomicAdd(&deg_src[src[i]], 1);
    atomicAdd(&deg_dst[dst[i]], 1);
  }
}

__global__ void cinv_kernel(const int* __restrict__ deg_src, const int* __restrict__ deg_dst,
                            float* __restrict__ c_src, float* __restrict__ c_dst, int n) {
  int i = blockIdx.x * blockDim.x + threadIdx.x;
  if (i < n) {
    int ds = deg_src[i];
    int dd = deg_dst[i];
    c_src[i] = ds > 0 ? 1.0f / sqrtf((float)ds) : 0.0f;
    c_dst[i] = dd > 0 ? 1.0f / sqrtf((float)dd) : 0.0f;
  }
}

// 256-thread block inclusive scan (4 waves). lds must hold 4 ints.
__device__ __forceinline__ int block_incl_scan(int v, int* lds) {
  int lane = threadIdx.x & 63;
  int wid = threadIdx.x >> 6;
  int x = v;
  #pragma unroll
  for (int o = 1; o < 64; o <<= 1) {
    int y = __shfl_up(x, o, 64);
    if (lane >= o) x += y;
  }
  if (lane == 63) lds[wid] = x;
  __syncthreads();
  int off = 0;
  #pragma unroll
  for (int w = 0; w < 4; ++w)
    if (w < wid) off += lds[w];
  return x + off;
}

__global__ void deg_partial_kernel(const int* __restrict__ deg, int* __restrict__ partials, int n) {
  __shared__ int lds[4];
  int i = blockIdx.x * 256 + threadIdx.x;
  int v = (i < n) ? deg[i] : 0;
  int x = v;
  #pragma unroll
  for (int o = 1; o < 64; o <<= 1) x += __shfl_xor(x, o, 64);
  if ((threadIdx.x & 63) == 0) lds[threadIdx.x >> 6] = x;
  __syncthreads();
  if (threadIdx.x == 0) partials[blockIdx.x] = lds[0] + lds[1] + lds[2] + lds[3];
}

__global__ void scan_partials_kernel(int* __restrict__ partials, int* __restrict__ row_ptr,
                                     int nb, int n) {
  __shared__ int lds[4];
  int t = threadIdx.x;
  int v = (t < nb) ? partials[t] : 0;
  int incl = block_incl_scan(v, lds);
  if (t < nb) partials[t] = incl - v;  // exclusive
  if (t == 255) row_ptr[n] = incl;     // total
}

__global__ void final_scan_kernel(const int* __restrict__ deg, const int* __restrict__ partials,
                                  int* __restrict__ row_ptr, int* __restrict__ cursor, int n) {
  __shared__ int lds[4];
  int i = blockIdx.x * 256 + threadIdx.x;
  int v = (i < n) ? deg[i] : 0;
  int incl = block_incl_scan(v, lds);
  int excl = incl - v + partials[blockIdx.x];
  if (i < n) {
    row_ptr[i] = excl;
    cursor[i] = excl;
  }
}

__global__ void fill_csr_kernel(const int* __restrict__ src, const int* __restrict__ dst,
                                int* __restrict__ cursor, int* __restrict__ csr_src, int E) {
  int i = blockIdx.x * blockDim.x + threadIdx.x;
  if (i < E) {
    int slot = atomicAdd(&cursor[dst[i]], 1);
    csr_src[slot] = src[i];
  }
}

// ---------------- fp32 -> fp16 convert ----------------

__global__ void f32_to_f16_kernel(const float* __restrict__ in, _Float16* __restrict__ out,
                                  long n4) {
  long i = (long)blockIdx.x * blockDim.x + threadIdx.x;
  long stride = (long)gridDim.x * blockDim.x;
  for (; i < n4; i += stride) {
    float4 v = ((const float4*)in)[i];
    f16x4 h;
    h.x = (_Float16)v.x; h.y = (_Float16)v.y; h.z = (_Float16)v.z; h.w = (_Float16)v.w;
    ((f16x4*)out)[i] = h;
  }
}

// ---------------- aggregation (fp16 in, fp32 accum, fp16 out) ----------------
template <typename VT, int NE, int G>
__global__ void agg16_kernel(const _Float16* __restrict__ in, _Float16* __restrict__ out,
                             const int* __restrict__ row_ptr, const int* __restrict__ csr_src,
                             const float* __restrict__ c_src, const float* __restrict__ c_dst) {
  int d = blockIdx.x;
  int t = threadIdx.x;
  if (t >= G) return;
  int beg = row_ptr[d];
  int cnt = row_ptr[d + 1] - beg;
  const VT* inv = (const VT*)in;
  float acc[NE];
  #pragma unroll
  for (int e = 0; e < NE; ++e) acc[e] = 0.f;

  VT vA{}, vB{};
  float cA = 0.f, cB = 0.f;
  if (cnt > 0) { int s = csr_src[beg];     cA = c_src[s]; vA = inv[(size_t)s * G + t]; }
  if (cnt > 1) { int s = csr_src[beg + 1]; cB = c_src[s]; vB = inv[(size_t)s * G + t]; }
  for (int k = 0; k < cnt; ++k) {
    VT vN{};
    float cN = 0.f;
    if (k + 2 < cnt) { int s = csr_src[beg + k + 2]; cN = c_src[s]; vN = inv[(size_t)s * G + t]; }
    #pragma unroll
    for (int e = 0; e < NE; ++e) acc[e] = fmaf(cA, (float)vA[e], acc[e]);
    vA = vB; cA = cB;
    vB = vN; cB = cN;
  }
  float cd = c_dst[d];
  VT o;
  #pragma unroll
  for (int e = 0; e < NE; ++e) o[e] = (_Float16)(acc[e] * cd);
  __builtin_nontemporal_store(o, (VT*)out + (size_t)d * G + t);
}

// fp16 in -> fp32 out with bias (final 40-dim aggregation).
__global__ void agg40_kernel(const _Float16* __restrict__ in, float* __restrict__ out,
                             const int* __restrict__ row_ptr, const int* __restrict__ csr_src,
                             const float* __restrict__ c_src, const float* __restrict__ c_dst,
                             const float* __restrict__ bias) {
  int d = blockIdx.x;
  int t = threadIdx.x;
  if (t >= 10) return;
  int beg = row_ptr[d];
  int cnt = row_ptr[d + 1] - beg;
  const f16x4* in4 = (const f16x4*)in;
  float ax = 0.f, ay = 0.f, az = 0.f, aw = 0.f;

  f16x4 vA{}, vB{};
  float cA = 0.f, cB = 0.f;
  if (cnt > 0) { int s = csr_src[beg];     cA = c_src[s]; vA = in4[(size_t)s * 10 + t]; }
  if (cnt > 1) { int s = csr_src[beg + 1]; cB = c_src[s]; vB = in4[(size_t)s * 10 + t]; }
  for (int k = 0; k < cnt; ++k) {
    f16x4 vN{};
    float cN = 0.f;
    if (k + 2 < cnt) { int s = csr_src[beg + k + 2]; cN = c_src[s]; vN = in4[(size_t)s * 10 + t]; }
    ax = fmaf(cA, (float)vA.x, ax);
    ay = fmaf(cA, (float)vA.y, ay);
    az = fmaf(cA, (float)vA.z, az);
    aw = fmaf(cA, (float)vA.w, aw);
    vA = vB; cA = cB;
    vB = vN; cB = cN;
  }
  float cd = c_dst[d];
  float4 b = ((const float4*)bias)[t];
  f32x4 o;
  o[0] = ax * cd + b.x;
  o[1] = ay * cd + b.y;
  o[2] = az * cd + b.z;
  o[3] = aw * cd + b.w;
  __builtin_nontemporal_store(o, (f32x4*)out + (size_t)d * 10 + t);
}

// ---------------- weight prep: W[K][N] fp32 -> Wt fp16 [N][K] ----------------

__global__ void prep_weight_kernel(const float* __restrict__ W, _Float16* __restrict__ th,
                                   int K, int N) {
  __shared__ float tile[32][33];
  int bn = blockIdx.x * 32, bk = blockIdx.y * 32;
  int tx = threadIdx.x, ty = threadIdx.y;  // (32, 8)
  #pragma unroll
  for (int i = 0; i < 4; ++i)
    tile[ty + i * 8][tx] = W[(size_t)(bk + ty + i * 8) * N + bn + tx];
  __syncthreads();
  #pragma unroll
  for (int i = 0; i < 4; ++i) {
    float v = tile[tx][ty + i * 8];           // = W[bk+tx][bn+ty+i*8]
    th[(size_t)(bn + ty + i * 8) * K + bk + tx] = (_Float16)v;  // Wt[n][k]
  }
}

// ---------------- single-term fp16 MFMA GEMM, 8 waves, BK=64 ----------------
// C16[M][N] = relu( A[M][K](fp16) * B^T[N][K](fp16) + bias )
// 128x128 tile, BK=64 (two stacked BK=32 halves, same swizzle per half),
// 512 thr = 8 waves (2Mx4N), 4x2 frags/wave, acc = 32 regs/thread.
__global__ __launch_bounds__(512, 4) void mfma_gemm_kernel(
    const _Float16* __restrict__ A, const _Float16* __restrict__ B,
    const float* __restrict__ bias, _Float16* __restrict__ C,
    int M, int K, int N) {
  __shared__ _Float16 sA[2 * 128 * 32], sB[2 * 128 * 32];
  int t = threadIdx.x;
  int lane = t & 63, wid = t >> 6;
  int wr = wid >> 2, wc = wid & 3;        // 2 x 4 wave grid
  int lr = lane & 15, ko = lane >> 4;
  int swz = (lr & 3) ^ ((lr >> 2) & 3);
  int koff = ((ko ^ swz) << 3);           // fp16 units within a 32-elem row
  int bm = blockIdx.x * 128, bn = blockIdx.y * 128;

  f32x4 acc[4][2] = {};

  int aoff[4], boff[2];
  #pragma unroll
  for (int i = 0; i < 4; ++i) aoff[i] = (wr * 64 + i * 16 + lr) * 32 + koff;
  #pragma unroll
  for (int j = 0; j < 2; ++j) boff[j] = (wc * 32 + j * 16 + lr) * 32 + koff;

  int srow = t >> 2;
  int sc = (t & 3) ^ ((srow & 3) ^ ((srow >> 2) & 3));
  int ldst = wid * 512;  // fp16 units within an 8K-half; wave-uniform base
  int gra = bm + srow;
  if (gra >= M) gra = M - 1;
  size_t gabase = (size_t)gra * K + sc * 8;
  size_t gbbase = (size_t)(bn + srow) * K + sc * 8;  // N%128==0 for these layers

  for (int k0 = 0; k0 < K; k0 += 64) {
    #pragma unroll
    for (int ks = 0; ks < 2; ++ks) {
      int gofs = k0 + ks * 32;
      int lofs = ks * 4096 + ldst;
      gload_lds16(A + gabase + gofs, sA + lofs);
      gload_lds16(B + gbbase + gofs, sB + lofs);
    }
    __syncthreads();
    #pragma unroll
    for (int ks = 0; ks < 2; ++ks) {
      int lofs = ks * 4096;
      f16x8 a[4], b[2];
      #pragma unroll
      for (int i = 0; i < 4; ++i) a[i] = *(const f16x8*)(sA + lofs + aoff[i]);
      #pragma unroll
      for (int j = 0; j < 2; ++j) b[j] = *(const f16x8*)(sB + lofs + boff[j]);
      #pragma unroll
      for (int i = 0; i < 4; ++i)
        #pragma unroll
        for (int j = 0; j < 2; ++j)
          acc[i][j] = __builtin_amdgcn_mfma_f32_16x16x32_f16(a[i], b[j], acc[i][j], 0, 0, 0);
    }
    __syncthreads();
  }

  int r0 = (lane >> 4) << 2;
  #pragma unroll
  for (int i = 0; i < 4; ++i) {
    #pragma unroll
    for (int j = 0; j < 2; ++j) {
      int col = bn + wc * 32 + j * 16 + lr;
      float bv = bias[col];
      #pragma unroll
      for (int r = 0; r < 4; ++r) {
        int row = bm + wr * 64 + i * 16 + r0 + r;
        if (row < M) {
          float v = acc[i][j][r] + bv;
          v = v > 0.f ? v : 0.f;
          C[(size_t)row * N + col] = (_Float16)v;  // cached: next agg gathers this
        }
      }
    }
  }
}

// ---------------- fp32 VALU GEMM, fp16 A and C (layer 4, N=40) ----------------

__global__ __launch_bounds__(256) void gemm40_kernel(const _Float16* __restrict__ A,
                                                     const float* __restrict__ W,
                                                     _Float16* __restrict__ C,
                                                     int M, int K, int N) {
  __shared__ float As[16][128 + 4];
  __shared__ float Bs[16][128 + 4];
  int tid = threadIdx.x;
  int tx = tid & 15;
  int ty = tid >> 4;
  int bm = blockIdx.x * 128;
  int bn = blockIdx.y * 128;

  float acc[8][8];
  #pragma unroll
  for (int i = 0; i < 8; ++i)
    #pragma unroll
    for (int j = 0; j < 8; ++j) acc[i][j] = 0.f;

  int ar = tid >> 2;
  int akq = (tid & 3) << 2;
  int bkk = tid >> 4;
  int bcq = (tid & 15) << 2;

  for (int k0 = 0; k0 < K; k0 += 16) {
    #pragma unroll
    for (int half = 0; half < 2; ++half) {
      int r = ar + half * 64;
      int grow = bm + r;
      float4 v = make_float4(0.f, 0.f, 0.f, 0.f);
      if (grow < M) {
        f16x4 hv = *(const f16x4*)&A[(size_t)grow * K + k0 + akq];
        v = make_float4((float)hv.x, (float)hv.y, (float)hv.z, (float)hv.w);
      }
      As[akq + 0][r] = v.x;
      As[akq + 1][r] = v.y;
      As[akq + 2][r] = v.z;
      As[akq + 3][r] = v.w;
    }
    #pragma unroll
    for (int half = 0; half < 2; ++half) {
      int c = bcq + half * 64;
      int gc = bn + c;
      float4 v = make_float4(0.f, 0.f, 0.f, 0.f);
      if (gc + 3 < N) v = *(const float4*)&W[(size_t)(k0 + bkk) * N + gc];
      *(float4*)&Bs[bkk][c] = v;
    }
    __syncthreads();
    #pragma unroll
    for (int kk = 0; kk < 16; ++kk) {
      float4 a0 = *(const float4*)&As[kk][ty * 4];
      float4 a1 = *(const float4*)&As[kk][ty * 4 + 64];
      float4 b0 = *(const float4*)&Bs[kk][tx * 4];
      float4 b1 = *(const float4*)&Bs[kk][tx * 4 + 64];
      float a[8] = {a0.x, a0.y, a0.z, a0.w, a1.x, a1.y, a1.z, a1.w};
      float b[8] = {b0.x, b0.y, b0.z, b0.w, b1.x, b1.y, b1.z, b1.w};
      #pragma unroll
      for (int i = 0; i < 8; ++i)
        #pragma unroll
        for (int j = 0; j < 8; ++j) acc[i][j] = fmaf(a[i], b[j], acc[i][j]);
    }
    __syncthreads();
  }

  #pragma unroll
  for (int i = 0; i < 8; ++i) {
    int r = bm + (i < 4 ? ty * 4 + i : 64 + ty * 4 + (i - 4));
    if (r >= M) continue;
    #pragma unroll
    for (int j = 0; j < 8; ++j) {
      int c = bn + (j < 4 ? tx * 4 + j : 64 + tx * 4 + (j - 4));
      if (c >= N) continue;
      C[(size_t)r * N + c] = (_Float16)acc[i][j];
    }
  }
}

// ---------------- launch ----------------

extern "C" void kernel_launch(void* const* d_in, const int* in_sizes, int n_in,
                              void* d_out, int out_size, void* d_ws, size_t ws_size,
                              hipStream_t stream) {
  const float* x  = (const float*)d_in[0];
  const int* src  = (const int*)d_in[1];
  const int* dst  = (const int*)d_in[2];
  const float* W1 = (const float*)d_in[3];
  const float* b1 = (const float*)d_in[4];
  const float* W2 = (const float*)d_in[5];
  const float* b2 = (const float*)d_in[6];
  const float* W3 = (const float*)d_in[7];
  const float* b3 = (const float*)d_in[8];
  const float* W4 = (const float*)d_in[9];
  const float* b4 = (const float*)d_in[10];
  float* out = (float*)d_out;

  const int N = GCN_N, E = GCN_E;
  const int NB = (N + 255) / 256;  // 196 scan chunks

  char* ws = (char*)d_ws;
  size_t off = 0;
  _Float16* h16a = (_Float16*)(ws + off); off += (size_t)N * 512 * 2;  // agg out / GEMM A
  _Float16* h16b = (_Float16*)(ws + off); off += (size_t)N * 512 * 2;  // GEMM out / agg in
  _Float16* x16  = (_Float16*)(ws + off); off += (size_t)N * 256 * 2;
  float* c_src = (float*)(ws + off); off += (size_t)N * 4;
  float* c_dst = (float*)(ws + off); off += (size_t)N * 4;
  int* row_ptr = (int*)(ws + off); off += (size_t)(N + 4) * 4;
  int* csr_src = (int*)(ws + off); off += (size_t)E * 4;
  int* partials = (int*)(ws + off); off += 256 * 4;
  _Float16* WtH1 = (_Float16*)(ws + off); off += (size_t)512 * 256 * 2;
  _Float16* WtH2 = (_Float16*)(ws + off); off += (size_t)512 * 512 * 2;
  _Float16* WtH3 = (_Float16*)(ws + off); off += (size_t)512 * 512 * 2;
  // transients alias h16a (dead before L1 agg writes h16a)
  int* deg_src = (int*)h16a;
  int* deg_dst = deg_src + N;
  int* cursor  = deg_dst + N;
  // t4 [N][40] fp16 aliases x16 (x16 dead after L1 agg)
  _Float16* t4 = x16;

  hipMemsetAsync(deg_src, 0, (size_t)2 * N * 4, stream);
  hist_kernel<<<(E + 255) / 256, 256, 0, stream>>>(src, dst, deg_src, deg_dst, E);
  cinv_kernel<<<(N + 255) / 256, 256, 0, stream>>>(deg_src, deg_dst, c_src, c_dst, N);
  deg_partial_kernel<<<NB, 256, 0, stream>>>(deg_dst, partials, N);
  scan_partials_kernel<<<1, 256, 0, stream>>>(partials, row_ptr, NB, N);
  final_scan_kernel<<<NB, 256, 0, stream>>>(deg_dst, partials, row_ptr, cursor, N);
  fill_csr_kernel<<<(E + 255) / 256, 256, 0, stream>>>(src, dst, cursor, csr_src, E);

  prep_weight_kernel<<<dim3(16, 8), dim3(32, 8), 0, stream>>>(W1, WtH1, 256, 512);
  prep_weight_kernel<<<dim3(16, 16), dim3(32, 8), 0, stream>>>(W2, WtH2, 512, 512);
  prep_weight_kernel<<<dim3(16, 16), dim3(32, 8), 0, stream>>>(W3, WtH3, 512, 512);

  f32_to_f16_kernel<<<2048, 256, 0, stream>>>(x, x16, (long)N * 256 / 4);

  int gm = (N + 127) / 128;  // 391

  // L1: agg 256-dim (f16x4, 64 thr), GEMM K=256
  agg16_kernel<f16x4, 4, 64><<<N, 64, 0, stream>>>(x16, h16a, row_ptr, csr_src, c_src, c_dst);
  mfma_gemm_kernel<<<dim3(gm, 4), 512, 0, stream>>>(h16a, WtH1, b1, h16b, N, 256, 512);
  // L2: agg 512-dim (f16x8, 64 thr = 16B/lane)
  agg16_kernel<f16x8, 8, 64><<<N, 64, 0, stream>>>(h16b, h16a, row_ptr, csr_src, c_src, c_dst);
  mfma_gemm_kernel<<<dim3(gm, 4), 512, 0, stream>>>(h16a, WtH2, b2, h16b, N, 512, 512);
  // L3
  agg16_kernel<f16x8, 8, 64><<<N, 64, 0, stream>>>(h16b, h16a, row_ptr, csr_src, c_src, c_dst);
  mfma_gemm_kernel<<<dim3(gm, 4), 512, 0, stream>>>(h16a, WtH3, b3, h16b, N, 512, 512);
  // L4
  gemm40_kernel<<<dim3(gm, 1), 256, 0, stream>>>(h16b, W4, t4, N, 512, 40);
  agg40_kernel<<<N, 64, 0, stream>>>(t4, out, row_ptr, csr_src, c_src, c_dst, b4);
}